// Round 1
// baseline (1892.464 us; speedup 1.0000x reference)
//
#include <hip/hip_runtime.h>
#include <hip/hip_bf16.h>

#define EMB 1024
#define THREE_EMB 3072
#define T_SEQ 2048
#define NB 4
#define NH 16
#define HD 64
#define MROWS 8192  // NB * T_SEQ

// ---------------------------------------------------------------------------
// Tiled fp32 GEMM: C[M,N] = X[M,1024] @ W[1024,N] + bias
// 128x128 tile, BK=8, 256 threads, 8x8 per-thread microtile (as 4 quads of 4x4
// at (ty*4 / 64+ty*4) x (tx*4 / 64+tx*4) to keep LDS reads 2-way/broadcast).
// MODE 0: N=3072, scatter to Q/K/V in [B,H,T,D] layout, Q scaled by 0.125.
// MODE 1: N=1024, plain output + bias.
// ---------------------------------------------------------------------------
template <int MODE>
__global__ __launch_bounds__(256) void gemm_kernel(
    const float* __restrict__ X, const float* __restrict__ W,
    const float* __restrict__ bias, float* __restrict__ O0,
    float* __restrict__ O1, float* __restrict__ O2) {
  constexpr int N = (MODE == 0) ? THREE_EMB : EMB;
  constexpr int Kd = EMB;
  __shared__ float As[8][128];  // transposed: As[k][m]
  __shared__ float Bs[8][128];  // Bs[k][n]

  const int tid = threadIdx.x;
  const int m0 = blockIdx.x * 128;
  const int n0 = blockIdx.y * 128;
  const int tx = tid & 15;
  const int ty = tid >> 4;
  const int la_r = tid >> 1;         // 0..127
  const int la_c = (tid & 1) * 4;    // 0 or 4
  const int lb_r = tid >> 5;         // 0..7
  const int lb_c = (tid & 31) * 4;   // 0..124

  float acc[8][8];
#pragma unroll
  for (int i = 0; i < 8; ++i)
#pragma unroll
    for (int j = 0; j < 8; ++j) acc[i][j] = 0.f;

  const float* xp = X + (size_t)(m0 + la_r) * Kd + la_c;
  const float* wp = W + (size_t)lb_r * N + n0 + lb_c;

  for (int k0 = 0; k0 < Kd; k0 += 8) {
    const float4 av = *(const float4*)(xp + k0);
    const float4 bv = *(const float4*)(wp + (size_t)k0 * N);
    __syncthreads();  // previous iteration's reads complete
    As[la_c + 0][la_r] = av.x;
    As[la_c + 1][la_r] = av.y;
    As[la_c + 2][la_r] = av.z;
    As[la_c + 3][la_r] = av.w;
    *(float4*)&Bs[lb_r][lb_c] = bv;
    __syncthreads();
#pragma unroll
    for (int k = 0; k < 8; ++k) {
      float a[8], b[8];
      *(float4*)&a[0] = *(const float4*)&As[k][ty * 4];
      *(float4*)&a[4] = *(const float4*)&As[k][64 + ty * 4];
      *(float4*)&b[0] = *(const float4*)&Bs[k][tx * 4];
      *(float4*)&b[4] = *(const float4*)&Bs[k][64 + tx * 4];
#pragma unroll
      for (int i = 0; i < 8; ++i)
#pragma unroll
        for (int j = 0; j < 8; ++j) acc[i][j] = fmaf(a[i], b[j], acc[i][j]);
    }
  }

#pragma unroll
  for (int i = 0; i < 8; ++i) {
    const int gi = (i < 4) ? (ty * 4 + i) : (64 + ty * 4 + (i - 4));
    const int gm = m0 + gi;
#pragma unroll
    for (int jq = 0; jq < 2; ++jq) {
      const int cj = (jq == 0) ? (tx * 4) : (64 + tx * 4);
      const int gn = n0 + cj;
      float4 v;
      v.x = acc[i][jq * 4 + 0] + bias[gn + 0];
      v.y = acc[i][jq * 4 + 1] + bias[gn + 1];
      v.z = acc[i][jq * 4 + 2] + bias[gn + 2];
      v.w = acc[i][jq * 4 + 3] + bias[gn + 3];
      if (MODE == 1) {
        *(float4*)&O0[(size_t)gm * EMB + gn] = v;
      } else {
        const int which = gn >> 10;  // 0:Q 1:K 2:V (uniform per block)
        const int e = gn & 1023;
        const int h = e >> 6;
        const int d = e & 63;
        const int b = gm >> 11;
        const int t = gm & 2047;
        const size_t idx = ((size_t)(b * NH + h) * T_SEQ + t) * HD + d;
        if (which == 0) {
          v.x *= 0.125f; v.y *= 0.125f; v.z *= 0.125f; v.w *= 0.125f;
          *(float4*)&O0[idx] = v;
        } else if (which == 1) {
          *(float4*)&O1[idx] = v;
        } else {
          *(float4*)&O2[idx] = v;
        }
      }
    }
  }
}

// ---------------------------------------------------------------------------
// Flash-style attention, fp32. One block = one (b,h) and one 64-row Q tile.
// 256 threads; thread owns a 4x4 score/output microtile:
//   rows r4..r4+3 (r4 = (tid>>4)*4), cols c4..c4+3 (c4 = (tid&15)*4).
// K and Q staged transposed in LDS ([d][row]) so inner reads are
// broadcast / 2-way bank patterns. Online softmax; P exchanged via LDS
// (wave-local: each wave owns 16 score rows -> no barrier needed for P).
// Q is pre-scaled by 1/sqrt(64) in the QKV GEMM.
// ---------------------------------------------------------------------------
__global__ __launch_bounds__(256) void attn_kernel(
    const float* __restrict__ Q, const float* __restrict__ K,
    const float* __restrict__ V, float* __restrict__ A) {
  __shared__ float Qst[64][68];  // [d][qrow]
  __shared__ float Kst[64][68];  // [d][krow]
  __shared__ float Vs[64][68];   // [krow][d]
  __shared__ float Pst[64][68];  // [krow][qrow]

  const int tid = threadIdx.x;
  const int bh = blockIdx.y;  // b*16 + h
  const int q0 = blockIdx.x * 64;
  const int b = bh >> 4;
  const int h = bh & 15;
  const float* Qb = Q + (size_t)bh * T_SEQ * HD;
  const float* Kb = K + (size_t)bh * T_SEQ * HD;
  const float* Vb = V + (size_t)bh * T_SEQ * HD;

  const int lrow = tid >> 2;        // 0..63
  const int lc0 = (tid & 3) * 16;   // 0,16,32,48
  const int r4 = (tid >> 4) * 4;    // 0..60
  const int c4 = (tid & 15) * 4;    // 0..60

  // stage Q tile transposed
#pragma unroll
  for (int j = 0; j < 16; j += 4) {
    const float4 v = *(const float4*)&Qb[(size_t)(q0 + lrow) * HD + lc0 + j];
    Qst[lc0 + j + 0][lrow] = v.x;
    Qst[lc0 + j + 1][lrow] = v.y;
    Qst[lc0 + j + 2][lrow] = v.z;
    Qst[lc0 + j + 3][lrow] = v.w;
  }

  float O[4][4];
  float m[4], l[4];
#pragma unroll
  for (int i = 0; i < 4; ++i) {
    m[i] = -1e30f;
    l[i] = 0.f;
#pragma unroll
    for (int j = 0; j < 4; ++j) O[i][j] = 0.f;
  }

  for (int kt = 0; kt < T_SEQ; kt += 64) {
    __syncthreads();  // previous tile fully consumed (also covers Q staging)
#pragma unroll
    for (int j = 0; j < 16; j += 4) {
      const float4 kv = *(const float4*)&Kb[(size_t)(kt + lrow) * HD + lc0 + j];
      Kst[lc0 + j + 0][lrow] = kv.x;
      Kst[lc0 + j + 1][lrow] = kv.y;
      Kst[lc0 + j + 2][lrow] = kv.z;
      Kst[lc0 + j + 3][lrow] = kv.w;
      const float4 vv = *(const float4*)&Vb[(size_t)(kt + lrow) * HD + lc0 + j];
      *(float4*)&Vs[lrow][lc0 + j] = vv;
    }
    __syncthreads();

    // scores: s[i][j] = sum_d Q[q0+r4+i][d] * K[kt+c4+j][d]   (Q pre-scaled)
    float s[4][4];
#pragma unroll
    for (int i = 0; i < 4; ++i)
#pragma unroll
      for (int j = 0; j < 4; ++j) s[i][j] = 0.f;
#pragma unroll 8
    for (int d = 0; d < 64; ++d) {
      const float4 q4 = *(const float4*)&Qst[d][r4];
      const float4 k4 = *(const float4*)&Kst[d][c4];
      const float* qa = &q4.x;
      const float* ka = &k4.x;
#pragma unroll
      for (int i = 0; i < 4; ++i)
#pragma unroll
        for (int j = 0; j < 4; ++j) s[i][j] = fmaf(qa[i], ka[j], s[i][j]);
    }

    // online softmax update (rows spread over 16 lanes: tid&15)
    float mx[4];
#pragma unroll
    for (int i = 0; i < 4; ++i) {
      mx[i] = fmaxf(fmaxf(s[i][0], s[i][1]), fmaxf(s[i][2], s[i][3]));
    }
#pragma unroll
    for (int off = 1; off < 16; off <<= 1)
#pragma unroll
      for (int i = 0; i < 4; ++i) mx[i] = fmaxf(mx[i], __shfl_xor(mx[i], off));

    float psum[4];
#pragma unroll
    for (int i = 0; i < 4; ++i) {
      const float mnew = fmaxf(m[i], mx[i]);
      const float scale = __expf(m[i] - mnew);
      m[i] = mnew;
      l[i] *= scale;
#pragma unroll
      for (int j = 0; j < 4; ++j) O[i][j] *= scale;
      psum[i] = 0.f;
#pragma unroll
      for (int j = 0; j < 4; ++j) {
        const float p = __expf(s[i][j] - mnew);
        s[i][j] = p;
        psum[i] += p;
      }
    }
#pragma unroll
    for (int off = 1; off < 16; off <<= 1)
#pragma unroll
      for (int i = 0; i < 4; ++i) psum[i] += __shfl_xor(psum[i], off);
#pragma unroll
    for (int i = 0; i < 4; ++i) l[i] += psum[i];

    // exchange P via LDS (wave-local rows -> in-wave DS ordering suffices)
#pragma unroll
    for (int i = 0; i < 4; ++i)
#pragma unroll
      for (int j = 0; j < 4; ++j) Pst[c4 + j][r4 + i] = s[i][j];

    // O += P @ V
#pragma unroll 8
    for (int k = 0; k < 64; ++k) {
      const float4 p4 = *(const float4*)&Pst[k][r4];
      const float4 v4 = *(const float4*)&Vs[k][c4];
      const float* pa = &p4.x;
      const float* va = &v4.x;
#pragma unroll
      for (int i = 0; i < 4; ++i)
#pragma unroll
        for (int j = 0; j < 4; ++j) O[i][j] = fmaf(pa[i], va[j], O[i][j]);
    }
  }

  // normalize and write merged-head A[b][t][h*64 + d]
#pragma unroll
  for (int i = 0; i < 4; ++i) {
    const float inv = 1.0f / l[i];
    float4 ov;
    ov.x = O[i][0] * inv;
    ov.y = O[i][1] * inv;
    ov.z = O[i][2] * inv;
    ov.w = O[i][3] * inv;
    *(float4*)&A[(size_t)(b * T_SEQ + q0 + r4 + i) * EMB + h * HD + c4] = ov;
  }
}

extern "C" void kernel_launch(void* const* d_in, const int* in_sizes, int n_in,
                              void* d_out, int out_size, void* d_ws,
                              size_t ws_size, hipStream_t stream) {
  const float* x = (const float*)d_in[0];
  const float* w_attn = (const float*)d_in[1];
  const float* b_attn = (const float*)d_in[2];
  const float* w_proj = (const float*)d_in[3];
  const float* b_proj = (const float*)d_in[4];
  float* out = (float*)d_out;

  float* ws = (float*)d_ws;
  const size_t SZ = (size_t)MROWS * EMB;  // 8388608 elements
  float* Qw = ws;
  float* Kw = ws + SZ;
  float* Vw = ws + 2 * SZ;
  float* Aw = ws + 3 * SZ;

  // QKV projection: [8192,1024] @ [1024,3072] -> Q/K/V in [B,H,T,D]
  gemm_kernel<0><<<dim3(64, 24), 256, 0, stream>>>(x, w_attn, b_attn, Qw, Kw, Vw);
  // attention: 64 (b,h) pairs x 32 q-tiles
  attn_kernel<<<dim3(32, 64), 256, 0, stream>>>(Qw, Kw, Vw, Aw);
  // output projection: [8192,1024] @ [1024,1024]
  gemm_kernel<1><<<dim3(64, 8), 256, 0, stream>>>(Aw, w_proj, b_proj, out,
                                                  nullptr, nullptr);
}

// Round 2
// 1109.434 us; speedup vs baseline: 1.7058x; 1.7058x over previous
//
#include <hip/hip_runtime.h>
#include <hip/hip_bf16.h>

#define EMB 1024
#define THREE_EMB 3072
#define T_SEQ 2048
#define NB 4
#define NH 16
#define HD 64
#define MROWS 8192  // NB * T_SEQ
#define NBH 64      // NB * NH

// 0.125 * log2(e): fold score scale AND exp->exp2 conversion into Q
#define QSCALE 0.18033688011112042f

typedef _Float16 half8 __attribute__((ext_vector_type(8)));
typedef _Float16 half4v __attribute__((ext_vector_type(4)));
typedef float f32x4v __attribute__((ext_vector_type(4)));

static __device__ __forceinline__ f32x4v mfma16(half8 a, half8 b, f32x4v c) {
  return __builtin_amdgcn_mfma_f32_16x16x32_f16(a, b, c, 0, 0, 0);
}

// ---------------------------------------------------------------------------
// fp32 GEMM (as round 1). MODE 0: QKV projection; epilogue emits
//   Qhi/Qlo f16 [bh][t][d] (scaled by QSCALE), Khi/Klo f16 [bh][t][d],
//   Vt f16 [bh][d][t] (transposed, single f16).
// MODE 1: plain fp32 out + bias.
// ---------------------------------------------------------------------------
template <int MODE>
__global__ __launch_bounds__(256) void gemm_kernel(
    const float* __restrict__ X, const float* __restrict__ W,
    const float* __restrict__ bias, float* __restrict__ OutF,
    _Float16* __restrict__ Qhi, _Float16* __restrict__ Qlo,
    _Float16* __restrict__ Khi, _Float16* __restrict__ Klo,
    _Float16* __restrict__ Vt) {
  constexpr int N = (MODE == 0) ? THREE_EMB : EMB;
  constexpr int Kd = EMB;
  __shared__ float As[8][128];
  __shared__ float Bs[8][128];

  const int tid = threadIdx.x;
  const int m0 = blockIdx.x * 128;
  const int n0 = blockIdx.y * 128;
  const int tx = tid & 15;
  const int ty = tid >> 4;
  const int la_r = tid >> 1;
  const int la_c = (tid & 1) * 4;
  const int lb_r = tid >> 5;
  const int lb_c = (tid & 31) * 4;

  float acc[8][8];
#pragma unroll
  for (int i = 0; i < 8; ++i)
#pragma unroll
    for (int j = 0; j < 8; ++j) acc[i][j] = 0.f;

  const float* xp = X + (size_t)(m0 + la_r) * Kd + la_c;
  const float* wp = W + (size_t)lb_r * N + n0 + lb_c;

  for (int k0 = 0; k0 < Kd; k0 += 8) {
    const float4 av = *(const float4*)(xp + k0);
    const float4 bv = *(const float4*)(wp + (size_t)k0 * N);
    __syncthreads();
    As[la_c + 0][la_r] = av.x;
    As[la_c + 1][la_r] = av.y;
    As[la_c + 2][la_r] = av.z;
    As[la_c + 3][la_r] = av.w;
    *(float4*)&Bs[lb_r][lb_c] = bv;
    __syncthreads();
#pragma unroll
    for (int k = 0; k < 8; ++k) {
      float a[8], b[8];
      *(float4*)&a[0] = *(const float4*)&As[k][ty * 4];
      *(float4*)&a[4] = *(const float4*)&As[k][64 + ty * 4];
      *(float4*)&b[0] = *(const float4*)&Bs[k][tx * 4];
      *(float4*)&b[4] = *(const float4*)&Bs[k][64 + tx * 4];
#pragma unroll
      for (int i = 0; i < 8; ++i)
#pragma unroll
        for (int j = 0; j < 8; ++j) acc[i][j] = fmaf(a[i], b[j], acc[i][j]);
    }
  }

#pragma unroll
  for (int i = 0; i < 8; ++i) {
    const int gi = (i < 4) ? (ty * 4 + i) : (64 + ty * 4 + (i - 4));
    const int gm = m0 + gi;
#pragma unroll
    for (int jq = 0; jq < 2; ++jq) {
      const int cj = (jq == 0) ? (tx * 4) : (64 + tx * 4);
      const int gn = n0 + cj;
      float va[4];
#pragma unroll
      for (int j = 0; j < 4; ++j) va[j] = acc[i][jq * 4 + j] + bias[gn + j];
      if (MODE == 1) {
        float4 v;
        v.x = va[0]; v.y = va[1]; v.z = va[2]; v.w = va[3];
        *(float4*)&OutF[(size_t)gm * EMB + gn] = v;
      } else {
        const int which = gn >> 10;  // 0:Q 1:K 2:V (uniform per block)
        const int e = gn & 1023;
        const int h = e >> 6;
        const int d = e & 63;
        const int b = gm >> 11;
        const int t = gm & 2047;
        const int bh = b * NH + h;
        if (which == 0) {
          const size_t idx = ((size_t)bh * T_SEQ + t) * HD + d;
          half4v hi, lo;
#pragma unroll
          for (int j = 0; j < 4; ++j) {
            const float q = va[j] * QSCALE;
            const _Float16 qh = (_Float16)q;
            hi[j] = qh;
            lo[j] = (_Float16)(q - (float)qh);
          }
          *(half4v*)&Qhi[idx] = hi;
          *(half4v*)&Qlo[idx] = lo;
        } else if (which == 1) {
          const size_t idx = ((size_t)bh * T_SEQ + t) * HD + d;
          half4v hi, lo;
#pragma unroll
          for (int j = 0; j < 4; ++j) {
            const _Float16 kh = (_Float16)va[j];
            hi[j] = kh;
            lo[j] = (_Float16)(va[j] - (float)kh);
          }
          *(half4v*)&Khi[idx] = hi;
          *(half4v*)&Klo[idx] = lo;
        } else {
          // transposed V: Vt[bh][d][t]
#pragma unroll
          for (int j = 0; j < 4; ++j)
            Vt[((size_t)bh * HD + d + j) * T_SEQ + t] = (_Float16)va[j];
        }
      }
    }
  }
}

// ---------------------------------------------------------------------------
// MFMA flash attention (f16 split). Block = 256 thr = 4 waves; each wave owns
// 16 q-rows of a 64-row q-tile for one (b,h). K-tile = 64 keys.
//   S = Qhi*Khi + Qlo*Khi + Qhi*Klo   (16x16x32 f16 MFMA, fp32 acc)
//   online softmax in C-layout regs (row r = (lane>>4)*4+reg, col = lane&15)
//   P -> f16 via LDS (wave-private), O += P * V (pure f16 MFMA)
// K/V LDS tiles: [row][8 chunks of 16B], chunk XOR-swizzled by (row&7) so
// B-fragment reads (16 lanes, stride-128B rows) are conflict-free.
// ---------------------------------------------------------------------------
__global__ __launch_bounds__(256) void attn_kernel(
    const _Float16* __restrict__ Qhi, const _Float16* __restrict__ Qlo,
    const _Float16* __restrict__ Khi, const _Float16* __restrict__ Klo,
    const _Float16* __restrict__ Vt, float* __restrict__ A) {
  __shared__ __align__(16) float4 KhiS[64 * 8];
  __shared__ __align__(16) float4 KloS[64 * 8];
  __shared__ __align__(16) float4 VtS[64 * 8];
  __shared__ __align__(16) _Float16 PS[4][16][72];

  const int tid = threadIdx.x;
  const int w = tid >> 6;
  const int lane = tid & 63;
  const int l15 = lane & 15;
  const int lhi = lane >> 4;  // 0..3
  const int bh = blockIdx.y;
  const int q0 = blockIdx.x * 64 + w * 16;
  const int b = bh >> 4;
  const int h = bh & 15;

  // Q fragments (A-layout: row=lane&15, k=(lane>>4)*8+j, two 32-wide k blocks)
  half8 qhi[2], qlo[2];
  {
    const size_t qbase = ((size_t)bh * T_SEQ + q0 + l15) * HD + lhi * 8;
    qhi[0] = *(const half8*)&Qhi[qbase];
    qhi[1] = *(const half8*)&Qhi[qbase + 32];
    qlo[0] = *(const half8*)&Qlo[qbase];
    qlo[1] = *(const half8*)&Qlo[qbase + 32];
  }

  f32x4v O[4];
  float m[4], l[4];
#pragma unroll
  for (int c = 0; c < 4; ++c) O[c] = (f32x4v){0.f, 0.f, 0.f, 0.f};
#pragma unroll
  for (int r = 0; r < 4; ++r) {
    m[r] = -1e30f;
    l[r] = 0.f;
  }

  // staging role: 4 threads per row, 2 chunks (16B) each
  const int srow = tid >> 2;       // 0..63
  const int c0 = (tid & 3) * 2;    // chunk base 0,2,4,6
  const size_t kgbase = (size_t)bh * T_SEQ * HD;
  const size_t vgbase = ((size_t)bh * HD + srow) * T_SEQ;

  for (int kt = 0; kt < T_SEQ; kt += 64) {
    // issue global loads before barrier (hide latency)
    const size_t krow = kgbase + (size_t)(kt + srow) * HD;
    const float4 g0 = *(const float4*)&Khi[krow + c0 * 8];
    const float4 g1 = *(const float4*)&Khi[krow + c0 * 8 + 8];
    const float4 g2 = *(const float4*)&Klo[krow + c0 * 8];
    const float4 g3 = *(const float4*)&Klo[krow + c0 * 8 + 8];
    const float4 g4 = *(const float4*)&Vt[vgbase + kt + c0 * 8];
    const float4 g5 = *(const float4*)&Vt[vgbase + kt + c0 * 8 + 8];
    __syncthreads();  // previous tile fully consumed
    const int sw = srow & 7;
    KhiS[srow * 8 + (c0 ^ sw)] = g0;
    KhiS[srow * 8 + ((c0 + 1) ^ sw)] = g1;
    KloS[srow * 8 + (c0 ^ sw)] = g2;
    KloS[srow * 8 + ((c0 + 1) ^ sw)] = g3;
    VtS[srow * 8 + (c0 ^ sw)] = g4;
    VtS[srow * 8 + ((c0 + 1) ^ sw)] = g5;
    __syncthreads();

    // ---- S = Q K^T (3-term f16 split) ----
    f32x4v s[4];
#pragma unroll
    for (int c = 0; c < 4; ++c) {
      s[c] = (f32x4v){0.f, 0.f, 0.f, 0.f};
      const int kcol = c * 16 + l15;
      const int ksw = kcol & 7;
#pragma unroll
      for (int m2 = 0; m2 < 2; ++m2) {
        const int ch = (lhi + 4 * m2) ^ ksw;
        const half8 kh = *(const half8*)&KhiS[kcol * 8 + ch];
        const half8 kl = *(const half8*)&KloS[kcol * 8 + ch];
        s[c] = mfma16(qhi[m2], kh, s[c]);
        s[c] = mfma16(qlo[m2], kh, s[c]);
        s[c] = mfma16(qhi[m2], kl, s[c]);
      }
    }

    // ---- online softmax (rows live on 16-lane groups) ----
    float mx[4];
#pragma unroll
    for (int r = 0; r < 4; ++r)
      mx[r] = fmaxf(fmaxf(s[0][r], s[1][r]), fmaxf(s[2][r], s[3][r]));
#pragma unroll
    for (int off = 1; off < 16; off <<= 1)
#pragma unroll
      for (int r = 0; r < 4; ++r) mx[r] = fmaxf(mx[r], __shfl_xor(mx[r], off));

    float psum[4];
#pragma unroll
    for (int r = 0; r < 4; ++r) {
      const float mn = fmaxf(m[r], mx[r]);
      const float sc = __builtin_amdgcn_exp2f(m[r] - mn);
      m[r] = mn;
      l[r] *= sc;
#pragma unroll
      for (int c = 0; c < 4; ++c) O[c][r] *= sc;
      psum[r] = 0.f;
#pragma unroll
      for (int c = 0; c < 4; ++c) {
        const float p = __builtin_amdgcn_exp2f(s[c][r] - mn);
        psum[r] += p;
        PS[w][lhi * 4 + r][c * 16 + l15] = (_Float16)p;
      }
    }
#pragma unroll
    for (int off = 1; off < 16; off <<= 1)
#pragma unroll
      for (int r = 0; r < 4; ++r) psum[r] += __shfl_xor(psum[r], off);
#pragma unroll
    for (int r = 0; r < 4; ++r) l[r] += psum[r];

    // ---- O += P V (pure f16) ----
    // P A-fragments (wave-private LDS; in-wave ds ordering via compiler waits)
    const half8 pa0 = *(const half8*)&PS[w][l15][lhi * 8];
    const half8 pa1 = *(const half8*)&PS[w][l15][lhi * 8 + 32];
#pragma unroll
    for (int c = 0; c < 4; ++c) {
      const int dcol = c * 16 + l15;
      const int dsw = dcol & 7;
      const half8 v0 = *(const half8*)&VtS[dcol * 8 + (lhi ^ dsw)];
      const half8 v1 = *(const half8*)&VtS[dcol * 8 + ((lhi + 4) ^ dsw)];
      O[c] = mfma16(pa0, v0, O[c]);
      O[c] = mfma16(pa1, v1, O[c]);
    }
  }

  // ---- normalize + write merged heads A[b][t][h*64+d] (fp32) ----
  float inv[4];
#pragma unroll
  for (int r = 0; r < 4; ++r) inv[r] = 1.0f / l[r];
#pragma unroll
  for (int c = 0; c < 4; ++c) {
#pragma unroll
    for (int r = 0; r < 4; ++r) {
      const int q = q0 + lhi * 4 + r;
      A[((size_t)(b * T_SEQ + q)) * EMB + h * HD + c * 16 + l15] =
          O[c][r] * inv[r];
    }
  }
}

extern "C" void kernel_launch(void* const* d_in, const int* in_sizes, int n_in,
                              void* d_out, int out_size, void* d_ws,
                              size_t ws_size, hipStream_t stream) {
  const float* x = (const float*)d_in[0];
  const float* w_attn = (const float*)d_in[1];
  const float* b_attn = (const float*)d_in[2];
  const float* w_proj = (const float*)d_in[3];
  const float* b_proj = (const float*)d_in[4];
  float* out = (float*)d_out;

  const size_t SZH = (size_t)NBH * T_SEQ * HD;  // 8388608 f16 elements (16MB)
  _Float16* Qhi = (_Float16*)d_ws;
  _Float16* Qlo = Qhi + SZH;
  _Float16* Khi = Qlo + SZH;
  _Float16* Klo = Khi + SZH;
  _Float16* Vt = Klo + SZH;
  float* Aw = (float*)(Vt + SZH);  // 32MB fp32; total ws use = 112MB

  // QKV projection (fp32 compute) + f16 split/transpose epilogue
  gemm_kernel<0><<<dim3(64, 24), 256, 0, stream>>>(x, w_attn, b_attn, nullptr,
                                                   Qhi, Qlo, Khi, Klo, Vt);
  // MFMA attention
  attn_kernel<<<dim3(32, NBH), 256, 0, stream>>>(Qhi, Qlo, Khi, Klo, Vt, Aw);
  // output projection (fp32)
  gemm_kernel<1><<<dim3(64, 8), 256, 0, stream>>>(Aw, w_proj, b_proj, out,
                                                  nullptr, nullptr, nullptr,
                                                  nullptr, nullptr);
}

// Round 3
// 459.410 us; speedup vs baseline: 4.1193x; 2.4149x over previous
//
#include <hip/hip_runtime.h>
#include <hip/hip_bf16.h>

#define EMB 1024
#define THREE_EMB 3072
#define T_SEQ 2048
#define NB 4
#define NH 16
#define HD 64
#define MROWS 8192  // NB * T_SEQ
#define NBH 64      // NB * NH

// 0.125 * log2(e): fold score scale AND exp->exp2 conversion into Q
#define QSCALE 0.18033688011112042f

typedef _Float16 half8 __attribute__((ext_vector_type(8)));
typedef _Float16 half4v __attribute__((ext_vector_type(4)));
typedef float f32x4v __attribute__((ext_vector_type(4)));

static __device__ __forceinline__ f32x4v mfma16(half8 a, half8 b, f32x4v c) {
  return __builtin_amdgcn_mfma_f32_16x16x32_f16(a, b, c, 0, 0, 0);
}

// async global->LDS, 16B per lane. LDS dest = wave-uniform base + lane*16.
static __device__ __forceinline__ void gload16(const void* g, void* l) {
  __builtin_amdgcn_global_load_lds(
      (const __attribute__((address_space(1))) void*)g,
      (__attribute__((address_space(3))) void*)l, 16, 0, 0);
}

// ---------------------------------------------------------------------------
// Pre-pass: split x (fp32) into f16 hi/lo, 8 elems/thread.
// ---------------------------------------------------------------------------
__global__ __launch_bounds__(256) void split_x(const float* __restrict__ X,
                                               _Float16* __restrict__ H,
                                               _Float16* __restrict__ L) {
  const size_t i = ((size_t)blockIdx.x * 256 + threadIdx.x) * 8;
  const float4 a = *(const float4*)&X[i];
  const float4 b = *(const float4*)&X[i + 4];
  const float va[8] = {a.x, a.y, a.z, a.w, b.x, b.y, b.z, b.w};
  half8 h, l;
#pragma unroll
  for (int j = 0; j < 8; ++j) {
    const _Float16 hh = (_Float16)va[j];
    h[j] = hh;
    l[j] = (_Float16)(va[j] - (float)hh);
  }
  *(half8*)&H[i] = h;
  *(half8*)&L[i] = l;
}

// ---------------------------------------------------------------------------
// Pre-pass: W [1024][N] fp32 -> Wt hi/lo [N][1024] f16 (32x32 LDS transpose).
// ---------------------------------------------------------------------------
__global__ __launch_bounds__(256) void tsplit_w(const float* __restrict__ W,
                                                _Float16* __restrict__ Th,
                                                _Float16* __restrict__ Tl,
                                                int N) {
  __shared__ float tile[32][33];
  const int tid = threadIdx.x;
  const int k0 = blockIdx.x * 32;
  const int n0 = blockIdx.y * 32;
  const int c = tid & 31;
  const int r4 = (tid >> 5) * 4;
#pragma unroll
  for (int rr = 0; rr < 4; ++rr)
    tile[r4 + rr][c] = W[(size_t)(k0 + r4 + rr) * N + n0 + c];
  __syncthreads();
#pragma unroll
  for (int rr = 0; rr < 4; ++rr) {
    const float v = tile[c][r4 + rr];
    const _Float16 hi = (_Float16)v;
    Th[(size_t)(n0 + r4 + rr) * EMB + k0 + c] = hi;
    Tl[(size_t)(n0 + r4 + rr) * EMB + k0 + c] = (_Float16)(v - (float)hi);
  }
}

// ---------------------------------------------------------------------------
// MFMA split-f16 GEMM: C = A @ B^T + bias, fp32 accum via 3-term f16 split.
//   A hi/lo: [M][1024] f16 row-major;  B hi/lo: [N][1024] f16 row-major.
// 128x128 tile, BK=64, 4 waves (2x2) of 64x64. Staging via global_load_lds
// (wave w stages one of {Ahi,Alo,Bhi,Blo}); LDS rows are 8 chunks of 16B,
// chunk slot XOR-swizzled by (row&7): inverse-swizzle applied on the GLOBAL
// source address (per-lane), swizzle applied on the ds_read side -> <=2-way.
// MODE 0: QKV epilogue (Q scaled+split, K split, V transposed f16).
// MODE 1: fp32 out + bias.
// ---------------------------------------------------------------------------
template <int MODE>
__global__ __launch_bounds__(256) void mfma_gemm(
    const _Float16* __restrict__ Ah, const _Float16* __restrict__ Al,
    const _Float16* __restrict__ Bh, const _Float16* __restrict__ Bl,
    const float* __restrict__ bias, float* __restrict__ OutF,
    _Float16* __restrict__ Qhi, _Float16* __restrict__ Qlo,
    _Float16* __restrict__ Khi, _Float16* __restrict__ Klo,
    _Float16* __restrict__ Vt) {
  __shared__ __align__(16) _Float16 sAh[128 * 64];
  __shared__ __align__(16) _Float16 sAl[128 * 64];
  __shared__ __align__(16) _Float16 sBh[128 * 64];
  __shared__ __align__(16) _Float16 sBl[128 * 64];

  const int tid = threadIdx.x;
  const int w = tid >> 6;
  const int lane = tid & 63;
  const int l15 = lane & 15;
  const int lhi = lane >> 4;
  const int wm = w >> 1, wn = w & 1;
  const int m0 = blockIdx.x * 128;
  const int n0 = blockIdx.y * 128;

  // staging: lane covers (row = i*8 + lane>>3, chunk = lane&7); source chunk
  // is (chunk ^ (row&7)) so LDS slot s of row r holds global chunk s^(r&7).
  const int rl = lane >> 3;
  const int cs8 = ((lane & 7) ^ rl) * 8;  // source k-offset within BK
  const _Float16* gs;
  _Float16* ls;
  if (w == 0) {
    gs = Ah + (size_t)m0 * EMB; ls = sAh;
  } else if (w == 1) {
    gs = Al + (size_t)m0 * EMB; ls = sAl;
  } else if (w == 2) {
    gs = Bh + (size_t)n0 * EMB; ls = sBh;
  } else {
    gs = Bl + (size_t)n0 * EMB; ls = sBl;
  }
  const _Float16* gl = gs + (size_t)rl * EMB + cs8;

  f32x4v acc[4][4];
#pragma unroll
  for (int mi = 0; mi < 4; ++mi)
#pragma unroll
    for (int ni = 0; ni < 4; ++ni) acc[mi][ni] = (f32x4v){0.f, 0.f, 0.f, 0.f};

  // read-side swizzled chunk slots (r&7 == l15&7 for all fragments)
  const int sb0 = ((lhi) ^ (l15 & 7)) * 8;
  const int sb1 = ((4 + lhi) ^ (l15 & 7)) * 8;

  for (int k0 = 0; k0 < EMB; k0 += 64) {
    __syncthreads();  // previous tile fully consumed
#pragma unroll
    for (int i = 0; i < 16; ++i)
      gload16(gl + k0 + i * 8 * EMB, ls + i * 512);
    __syncthreads();  // vmcnt(0) drained by compiler before barrier
#pragma unroll
    for (int kk = 0; kk < 2; ++kk) {
      const int sb = kk ? sb1 : sb0;
      half8 am[2][4], bn[2][4];
#pragma unroll
      for (int mi = 0; mi < 4; ++mi) {
        const int r = wm * 64 + mi * 16 + l15;
        am[0][mi] = *(const half8*)&sAh[r * 64 + sb];
        am[1][mi] = *(const half8*)&sAl[r * 64 + sb];
      }
#pragma unroll
      for (int ni = 0; ni < 4; ++ni) {
        const int r = wn * 64 + ni * 16 + l15;
        bn[0][ni] = *(const half8*)&sBh[r * 64 + sb];
        bn[1][ni] = *(const half8*)&sBl[r * 64 + sb];
      }
#pragma unroll
      for (int mi = 0; mi < 4; ++mi)
#pragma unroll
        for (int ni = 0; ni < 4; ++ni) {
          acc[mi][ni] = mfma16(am[0][mi], bn[0][ni], acc[mi][ni]);
          acc[mi][ni] = mfma16(am[1][mi], bn[0][ni], acc[mi][ni]);
          acc[mi][ni] = mfma16(am[0][mi], bn[1][ni], acc[mi][ni]);
        }
    }
  }

  // ---- epilogue ----
  // C layout: row = (lane>>4)*4 + reg, col = lane&15 (per 16x16 fragment)
  const int gmB = m0 + wm * 64 + lhi * 4;
  const int gnB = n0 + wn * 64 + l15;
  if (MODE == 1) {
#pragma unroll
    for (int mi = 0; mi < 4; ++mi)
#pragma unroll
      for (int ni = 0; ni < 4; ++ni) {
        const int gn = gnB + ni * 16;
        const float bi = bias[gn];
#pragma unroll
        for (int r = 0; r < 4; ++r) {
          const int gm = gmB + mi * 16 + r;
          OutF[(size_t)gm * EMB + gn] = acc[mi][ni][r] + bi;
        }
      }
  } else {
    const int which = n0 >> 10;  // 0:Q 1:K 2:V, uniform per block
#pragma unroll
    for (int mi = 0; mi < 4; ++mi) {
#pragma unroll
      for (int ni = 0; ni < 4; ++ni) {
        const int gn = gnB + ni * 16;
        const float bi = bias[gn];
        const int d = gn & 63;
        const int h = (gn >> 6) & 15;
        const int gm0 = gmB + mi * 16;
        const int b = gm0 >> 11;
        const int t0 = gm0 & 2047;
        const int bh = b * NH + h;
        if (which == 2) {
          half4v hv;
#pragma unroll
          for (int r = 0; r < 4; ++r) hv[r] = (_Float16)(acc[mi][ni][r] + bi);
          *(half4v*)&Vt[((size_t)bh * HD + d) * T_SEQ + t0] = hv;  // [bh][d][t]
        } else {
#pragma unroll
          for (int r = 0; r < 4; ++r) {
            float v = acc[mi][ni][r] + bi;
            if (which == 0) v *= QSCALE;
            const _Float16 hi = (_Float16)v;
            const _Float16 lo = (_Float16)(v - (float)hi);
            const size_t idx = ((size_t)bh * T_SEQ + t0 + r) * HD + d;
            if (which == 0) {
              Qhi[idx] = hi;
              Qlo[idx] = lo;
            } else {
              Khi[idx] = hi;
              Klo[idx] = lo;
            }
          }
        }
      }
    }
  }
}

// ---------------------------------------------------------------------------
// MFMA flash attention (unchanged from round 2 except f16 hi/lo output).
// ---------------------------------------------------------------------------
__global__ __launch_bounds__(256) void attn_kernel(
    const _Float16* __restrict__ Qhi, const _Float16* __restrict__ Qlo,
    const _Float16* __restrict__ Khi, const _Float16* __restrict__ Klo,
    const _Float16* __restrict__ Vt, _Float16* __restrict__ AOh,
    _Float16* __restrict__ AOl) {
  __shared__ __align__(16) float4 KhiS[64 * 8];
  __shared__ __align__(16) float4 KloS[64 * 8];
  __shared__ __align__(16) float4 VtS[64 * 8];
  __shared__ __align__(16) _Float16 PS[4][16][72];

  const int tid = threadIdx.x;
  const int w = tid >> 6;
  const int lane = tid & 63;
  const int l15 = lane & 15;
  const int lhi = lane >> 4;
  const int bh = blockIdx.y;
  const int q0 = blockIdx.x * 64 + w * 16;
  const int b = bh >> 4;
  const int h = bh & 15;

  half8 qhi[2], qlo[2];
  {
    const size_t qbase = ((size_t)bh * T_SEQ + q0 + l15) * HD + lhi * 8;
    qhi[0] = *(const half8*)&Qhi[qbase];
    qhi[1] = *(const half8*)&Qhi[qbase + 32];
    qlo[0] = *(const half8*)&Qlo[qbase];
    qlo[1] = *(const half8*)&Qlo[qbase + 32];
  }

  f32x4v O[4];
  float m[4], l[4];
#pragma unroll
  for (int c = 0; c < 4; ++c) O[c] = (f32x4v){0.f, 0.f, 0.f, 0.f};
#pragma unroll
  for (int r = 0; r < 4; ++r) {
    m[r] = -1e30f;
    l[r] = 0.f;
  }

  const int srow = tid >> 2;
  const int c0 = (tid & 3) * 2;
  const size_t kgbase = (size_t)bh * T_SEQ * HD;
  const size_t vgbase = ((size_t)bh * HD + srow) * T_SEQ;

  for (int kt = 0; kt < T_SEQ; kt += 64) {
    const size_t krow = kgbase + (size_t)(kt + srow) * HD;
    const float4 g0 = *(const float4*)&Khi[krow + c0 * 8];
    const float4 g1 = *(const float4*)&Khi[krow + c0 * 8 + 8];
    const float4 g2 = *(const float4*)&Klo[krow + c0 * 8];
    const float4 g3 = *(const float4*)&Klo[krow + c0 * 8 + 8];
    const float4 g4 = *(const float4*)&Vt[vgbase + kt + c0 * 8];
    const float4 g5 = *(const float4*)&Vt[vgbase + kt + c0 * 8 + 8];
    __syncthreads();
    const int sw = srow & 7;
    KhiS[srow * 8 + (c0 ^ sw)] = g0;
    KhiS[srow * 8 + ((c0 + 1) ^ sw)] = g1;
    KloS[srow * 8 + (c0 ^ sw)] = g2;
    KloS[srow * 8 + ((c0 + 1) ^ sw)] = g3;
    VtS[srow * 8 + (c0 ^ sw)] = g4;
    VtS[srow * 8 + ((c0 + 1) ^ sw)] = g5;
    __syncthreads();

    f32x4v s[4];
#pragma unroll
    for (int c = 0; c < 4; ++c) {
      s[c] = (f32x4v){0.f, 0.f, 0.f, 0.f};
      const int kcol = c * 16 + l15;
      const int ksw = kcol & 7;
#pragma unroll
      for (int m2 = 0; m2 < 2; ++m2) {
        const int ch = (lhi + 4 * m2) ^ ksw;
        const half8 kh = *(const half8*)&KhiS[kcol * 8 + ch];
        const half8 kl = *(const half8*)&KloS[kcol * 8 + ch];
        s[c] = mfma16(qhi[m2], kh, s[c]);
        s[c] = mfma16(qlo[m2], kh, s[c]);
        s[c] = mfma16(qhi[m2], kl, s[c]);
      }
    }

    float mx[4];
#pragma unroll
    for (int r = 0; r < 4; ++r)
      mx[r] = fmaxf(fmaxf(s[0][r], s[1][r]), fmaxf(s[2][r], s[3][r]));
#pragma unroll
    for (int off = 1; off < 16; off <<= 1)
#pragma unroll
      for (int r = 0; r < 4; ++r) mx[r] = fmaxf(mx[r], __shfl_xor(mx[r], off));

    float psum[4];
#pragma unroll
    for (int r = 0; r < 4; ++r) {
      const float mn = fmaxf(m[r], mx[r]);
      const float sc = __builtin_amdgcn_exp2f(m[r] - mn);
      m[r] = mn;
      l[r] *= sc;
#pragma unroll
      for (int c = 0; c < 4; ++c) O[c][r] *= sc;
      psum[r] = 0.f;
#pragma unroll
      for (int c = 0; c < 4; ++c) {
        const float p = __builtin_amdgcn_exp2f(s[c][r] - mn);
        psum[r] += p;
        PS[w][lhi * 4 + r][c * 16 + l15] = (_Float16)p;
      }
    }
#pragma unroll
    for (int off = 1; off < 16; off <<= 1)
#pragma unroll
      for (int r = 0; r < 4; ++r) psum[r] += __shfl_xor(psum[r], off);
#pragma unroll
    for (int r = 0; r < 4; ++r) l[r] += psum[r];

    const half8 pa0 = *(const half8*)&PS[w][l15][lhi * 8];
    const half8 pa1 = *(const half8*)&PS[w][l15][lhi * 8 + 32];
#pragma unroll
    for (int c = 0; c < 4; ++c) {
      const int dcol = c * 16 + l15;
      const int dsw = dcol & 7;
      const half8 v0 = *(const half8*)&VtS[dcol * 8 + (lhi ^ dsw)];
      const half8 v1 = *(const half8*)&VtS[dcol * 8 + ((lhi + 4) ^ dsw)];
      O[c] = mfma16(pa0, v0, O[c]);
      O[c] = mfma16(pa1, v1, O[c]);
    }
  }

  float inv[4];
#pragma unroll
  for (int r = 0; r < 4; ++r) inv[r] = 1.0f / l[r];
#pragma unroll
  for (int c = 0; c < 4; ++c) {
#pragma unroll
    for (int r = 0; r < 4; ++r) {
      const int q = q0 + lhi * 4 + r;
      const float v = O[c][r] * inv[r];
      const _Float16 hi = (_Float16)v;
      const size_t idx = (size_t)(b * T_SEQ + q) * EMB + h * HD + c * 16 + l15;
      AOh[idx] = hi;
      AOl[idx] = (_Float16)(v - (float)hi);
    }
  }
}

extern "C" void kernel_launch(void* const* d_in, const int* in_sizes, int n_in,
                              void* d_out, int out_size, void* d_ws,
                              size_t ws_size, hipStream_t stream) {
  const float* x = (const float*)d_in[0];
  const float* w_attn = (const float*)d_in[1];
  const float* b_attn = (const float*)d_in[2];
  const float* w_proj = (const float*)d_in[3];
  const float* b_proj = (const float*)d_in[4];
  float* out = (float*)d_out;

  const size_t SZX = (size_t)MROWS * EMB;   // 8388608
  const size_t SZWA = (size_t)THREE_EMB * EMB;
  const size_t SZWP = (size_t)EMB * EMB;

  _Float16* Xhi = (_Float16*)d_ws;
  _Float16* Xlo = Xhi + SZX;
  _Float16* WaHi = Xlo + SZX;
  _Float16* WaLo = WaHi + SZWA;
  _Float16* WpHi = WaLo + SZWA;
  _Float16* WpLo = WpHi + SZWP;
  _Float16* Qhi = WpLo + SZWP;
  _Float16* Qlo = Qhi + SZX;
  _Float16* Khi = Qlo + SZX;
  _Float16* Klo = Khi + SZX;
  _Float16* Vt = Klo + SZX;  // total 128 MiB
  // X region is dead after the QKV GEMM -> reuse for attention output
  _Float16* Ahi = Xhi;
  _Float16* Alo = Xlo;

  split_x<<<4096, 256, 0, stream>>>(x, Xhi, Xlo);
  tsplit_w<<<dim3(32, 96), 256, 0, stream>>>(w_attn, WaHi, WaLo, THREE_EMB);
  tsplit_w<<<dim3(32, 32), 256, 0, stream>>>(w_proj, WpHi, WpLo, EMB);

  mfma_gemm<0><<<dim3(64, 24), 256, 0, stream>>>(
      Xhi, Xlo, WaHi, WaLo, b_attn, nullptr, Qhi, Qlo, Khi, Klo, Vt);
  attn_kernel<<<dim3(32, NBH), 256, 0, stream>>>(Qhi, Qlo, Khi, Klo, Vt, Ahi,
                                                 Alo);
  mfma_gemm<1><<<dim3(64, 8), 256, 0, stream>>>(
      Ahi, Alo, WpHi, WpLo, b_proj, out, nullptr, nullptr, nullptr, nullptr,
      nullptr);
}

// Round 4
// 418.389 us; speedup vs baseline: 4.5232x; 1.0980x over previous
//
#include <hip/hip_runtime.h>
#include <hip/hip_bf16.h>

#define EMB 1024
#define THREE_EMB 3072
#define T_SEQ 2048
#define NB 4
#define NH 16
#define HD 64
#define MROWS 8192  // NB * T_SEQ
#define NBH 64      // NB * NH

// 0.125 * log2(e): fold score scale AND exp->exp2 conversion into Q
#define QSCALE 0.18033688011112042f

typedef _Float16 half8 __attribute__((ext_vector_type(8)));
typedef _Float16 half4v __attribute__((ext_vector_type(4)));
typedef float f32x4v __attribute__((ext_vector_type(4)));

static __device__ __forceinline__ f32x4v mfma16(half8 a, half8 b, f32x4v c) {
  return __builtin_amdgcn_mfma_f32_16x16x32_f16(a, b, c, 0, 0, 0);
}

// async global->LDS, 16B per lane. LDS dest = wave-uniform base + lane*16.
static __device__ __forceinline__ void gload16(const void* g, void* l) {
  __builtin_amdgcn_global_load_lds(
      (const __attribute__((address_space(1))) void*)g,
      (__attribute__((address_space(3))) void*)l, 16, 0, 0);
}

// ---------------------------------------------------------------------------
// Pre-pass: split x (fp32) into f16 hi/lo, 8 elems/thread.
// ---------------------------------------------------------------------------
__global__ __launch_bounds__(256) void split_x(const float* __restrict__ X,
                                               _Float16* __restrict__ H,
                                               _Float16* __restrict__ L) {
  const size_t i = ((size_t)blockIdx.x * 256 + threadIdx.x) * 8;
  const float4 a = *(const float4*)&X[i];
  const float4 b = *(const float4*)&X[i + 4];
  const float va[8] = {a.x, a.y, a.z, a.w, b.x, b.y, b.z, b.w};
  half8 h, l;
#pragma unroll
  for (int j = 0; j < 8; ++j) {
    const _Float16 hh = (_Float16)va[j];
    h[j] = hh;
    l[j] = (_Float16)(va[j] - (float)hh);
  }
  *(half8*)&H[i] = h;
  *(half8*)&L[i] = l;
}

// ---------------------------------------------------------------------------
// Pre-pass: W [1024][N] fp32 -> Wt hi/lo [N][1024] f16 (32x32 LDS transpose).
// ---------------------------------------------------------------------------
__global__ __launch_bounds__(256) void tsplit_w(const float* __restrict__ W,
                                                _Float16* __restrict__ Th,
                                                _Float16* __restrict__ Tl,
                                                int N) {
  __shared__ float tile[32][33];
  const int tid = threadIdx.x;
  const int k0 = blockIdx.x * 32;
  const int n0 = blockIdx.y * 32;
  const int c = tid & 31;
  const int r4 = (tid >> 5) * 4;
#pragma unroll
  for (int rr = 0; rr < 4; ++rr)
    tile[r4 + rr][c] = W[(size_t)(k0 + r4 + rr) * N + n0 + c];
  __syncthreads();
#pragma unroll
  for (int rr = 0; rr < 4; ++rr) {
    const float v = tile[c][r4 + rr];
    const _Float16 hi = (_Float16)v;
    Th[(size_t)(n0 + r4 + rr) * EMB + k0 + c] = hi;
    Tl[(size_t)(n0 + r4 + rr) * EMB + k0 + c] = (_Float16)(v - (float)hi);
  }
}

// ---------------------------------------------------------------------------
// MFMA split-f16 GEMM: C = A @ B^T + bias (3-term f16 split, fp32 accum).
// 128x128 tile, BK=64, 4 waves (2x2) of 64x64; global_load_lds staging with
// source-side inverse chunk-XOR swizzle, read-side swizzle -> <=2-way.
// MODE 0: QKV epilogue (Q hi/lo scaled, K single f16, V transposed f16).
// MODE 1: fp32 out + bias.
// ---------------------------------------------------------------------------
template <int MODE>
__global__ __launch_bounds__(256) void mfma_gemm(
    const _Float16* __restrict__ Ah, const _Float16* __restrict__ Al,
    const _Float16* __restrict__ Bh, const _Float16* __restrict__ Bl,
    const float* __restrict__ bias, float* __restrict__ OutF,
    _Float16* __restrict__ Qhi, _Float16* __restrict__ Qlo,
    _Float16* __restrict__ Kh, _Float16* __restrict__ Vt) {
  __shared__ __align__(16) _Float16 sAh[128 * 64];
  __shared__ __align__(16) _Float16 sAl[128 * 64];
  __shared__ __align__(16) _Float16 sBh[128 * 64];
  __shared__ __align__(16) _Float16 sBl[128 * 64];

  const int tid = threadIdx.x;
  const int w = tid >> 6;
  const int lane = tid & 63;
  const int l15 = lane & 15;
  const int lhi = lane >> 4;
  const int wm = w >> 1, wn = w & 1;
  const int m0 = blockIdx.x * 128;
  const int n0 = blockIdx.y * 128;

  const int rl = lane >> 3;
  const int cs8 = ((lane & 7) ^ rl) * 8;  // inverse-swizzled source k-offset
  const _Float16* gs;
  _Float16* ls;
  if (w == 0) {
    gs = Ah + (size_t)m0 * EMB; ls = sAh;
  } else if (w == 1) {
    gs = Al + (size_t)m0 * EMB; ls = sAl;
  } else if (w == 2) {
    gs = Bh + (size_t)n0 * EMB; ls = sBh;
  } else {
    gs = Bl + (size_t)n0 * EMB; ls = sBl;
  }
  const _Float16* gl = gs + (size_t)rl * EMB + cs8;

  f32x4v acc[4][4];
#pragma unroll
  for (int mi = 0; mi < 4; ++mi)
#pragma unroll
    for (int ni = 0; ni < 4; ++ni) acc[mi][ni] = (f32x4v){0.f, 0.f, 0.f, 0.f};

  const int sb0 = ((lhi) ^ (l15 & 7)) * 8;
  const int sb1 = ((4 + lhi) ^ (l15 & 7)) * 8;

  for (int k0 = 0; k0 < EMB; k0 += 64) {
    __syncthreads();
#pragma unroll
    for (int i = 0; i < 16; ++i)
      gload16(gl + k0 + i * 8 * EMB, ls + i * 512);
    __syncthreads();
#pragma unroll
    for (int kk = 0; kk < 2; ++kk) {
      const int sb = kk ? sb1 : sb0;
      half8 am[2][4], bn[2][4];
#pragma unroll
      for (int mi = 0; mi < 4; ++mi) {
        const int r = wm * 64 + mi * 16 + l15;
        am[0][mi] = *(const half8*)&sAh[r * 64 + sb];
        am[1][mi] = *(const half8*)&sAl[r * 64 + sb];
      }
#pragma unroll
      for (int ni = 0; ni < 4; ++ni) {
        const int r = wn * 64 + ni * 16 + l15;
        bn[0][ni] = *(const half8*)&sBh[r * 64 + sb];
        bn[1][ni] = *(const half8*)&sBl[r * 64 + sb];
      }
#pragma unroll
      for (int mi = 0; mi < 4; ++mi)
#pragma unroll
        for (int ni = 0; ni < 4; ++ni) {
          acc[mi][ni] = mfma16(am[0][mi], bn[0][ni], acc[mi][ni]);
          acc[mi][ni] = mfma16(am[1][mi], bn[0][ni], acc[mi][ni]);
          acc[mi][ni] = mfma16(am[0][mi], bn[1][ni], acc[mi][ni]);
        }
    }
  }

  // ---- epilogue ----  C layout: row=(lane>>4)*4+reg, col=lane&15
  const int gmB = m0 + wm * 64 + lhi * 4;
  const int gnB = n0 + wn * 64 + l15;
  if (MODE == 1) {
#pragma unroll
    for (int mi = 0; mi < 4; ++mi)
#pragma unroll
      for (int ni = 0; ni < 4; ++ni) {
        const int gn = gnB + ni * 16;
        const float bi = bias[gn];
#pragma unroll
        for (int r = 0; r < 4; ++r) {
          const int gm = gmB + mi * 16 + r;
          OutF[(size_t)gm * EMB + gn] = acc[mi][ni][r] + bi;
        }
      }
  } else {
    const int which = n0 >> 10;  // 0:Q 1:K 2:V, uniform per block
#pragma unroll
    for (int mi = 0; mi < 4; ++mi) {
#pragma unroll
      for (int ni = 0; ni < 4; ++ni) {
        const int gn = gnB + ni * 16;
        const float bi = bias[gn];
        const int d = gn & 63;
        const int h = (gn >> 6) & 15;
        const int gm0 = gmB + mi * 16;
        const int b = gm0 >> 11;
        const int t0 = gm0 & 2047;
        const int bh = b * NH + h;
        if (which == 2) {
          half4v hv;
#pragma unroll
          for (int r = 0; r < 4; ++r) hv[r] = (_Float16)(acc[mi][ni][r] + bi);
          *(half4v*)&Vt[((size_t)bh * HD + d) * T_SEQ + t0] = hv;  // [bh][d][t]
        } else if (which == 1) {
#pragma unroll
          for (int r = 0; r < 4; ++r) {
            const float v = acc[mi][ni][r] + bi;
            Kh[((size_t)bh * T_SEQ + t0 + r) * HD + d] = (_Float16)v;
          }
        } else {
#pragma unroll
          for (int r = 0; r < 4; ++r) {
            const float v = (acc[mi][ni][r] + bi) * QSCALE;
            const _Float16 hi = (_Float16)v;
            const size_t idx = ((size_t)bh * T_SEQ + t0 + r) * HD + d;
            Qhi[idx] = hi;
            Qlo[idx] = (_Float16)(v - (float)hi);
          }
        }
      }
    }
  }
}

// ---------------------------------------------------------------------------
// MFMA flash attention. Block = 4 waves x 32 q-rows = 128 q-rows per (b,h).
// K-tile = 64 keys. K single f16 (Q kept hi/lo in regs: Qlo*K term costs no
// LDS). K/V staged via global_load_lds with source-side inverse chunk-XOR
// swizzle; swizzled ds_reads -> <=2-way. Defer-max (THR=8, wave-uniform
// __all) skips the O-rescale on almost every tile.
// ---------------------------------------------------------------------------
__global__ __launch_bounds__(256) void attn_kernel(
    const _Float16* __restrict__ Qhi, const _Float16* __restrict__ Qlo,
    const _Float16* __restrict__ Kh, const _Float16* __restrict__ Vt,
    _Float16* __restrict__ AOh, _Float16* __restrict__ AOl) {
  __shared__ __align__(16) _Float16 KhS[64 * 64];
  __shared__ __align__(16) _Float16 VtS[64 * 64];
  __shared__ __align__(16) _Float16 PS[4][32][76];

  const int tid = threadIdx.x;
  const int w = tid >> 6;
  const int lane = tid & 63;
  const int l15 = lane & 15;
  const int lhi = lane >> 4;
  const int bh = blockIdx.y;
  const int q0 = blockIdx.x * 128 + w * 32;
  const int b = bh >> 4;
  const int h = bh & 15;

  // Q fragments for 2 sub-tiles of 16 rows (A-layout: row=l15, k=lhi*8+m2*32)
  half8 qh[2][2], ql[2][2];
#pragma unroll
  for (int qf = 0; qf < 2; ++qf) {
    const size_t qb = ((size_t)bh * T_SEQ + q0 + qf * 16 + l15) * HD + lhi * 8;
#pragma unroll
    for (int m2 = 0; m2 < 2; ++m2) {
      qh[qf][m2] = *(const half8*)&Qhi[qb + m2 * 32];
      ql[qf][m2] = *(const half8*)&Qlo[qb + m2 * 32];
    }
  }

  f32x4v O[2][4];
  float m[2][4], l[2][4];
#pragma unroll
  for (int qf = 0; qf < 2; ++qf)
#pragma unroll
    for (int c = 0; c < 4; ++c) O[qf][c] = (f32x4v){0.f, 0.f, 0.f, 0.f};
#pragma unroll
  for (int qf = 0; qf < 2; ++qf)
#pragma unroll
    for (int r = 0; r < 4; ++r) {
      m[qf][r] = -1e30f;
      l[qf][r] = 0.f;
    }

  // staging: wave w covers rows w*16+i*8+(lane>>3), slot lane&7;
  // source chunk = slot ^ (row&7)  (row&7 == lane>>3 here)
  const int so = lane >> 3;
  const int schunk = ((lane & 7) ^ so) * 8;  // element offset of source chunk
  const size_t kgb = (size_t)bh * T_SEQ * HD;
  const size_t vgb = (size_t)bh * HD * T_SEQ;

  for (int kt = 0; kt < T_SEQ; kt += 64) {
    __syncthreads();  // previous tile fully consumed
#pragma unroll
    for (int i = 0; i < 2; ++i) {
      const int row = w * 16 + i * 8 + so;
      gload16(Kh + kgb + (size_t)(kt + row) * HD + schunk,
              &KhS[(w * 16 + i * 8) * 64]);
      gload16(Vt + vgb + (size_t)row * T_SEQ + kt + schunk,
              &VtS[(w * 16 + i * 8) * 64]);
    }
    __syncthreads();

    // ---- S = Q K^T (Qhi*K + Qlo*K) ----
    f32x4v s[2][4];
#pragma unroll
    for (int c = 0; c < 4; ++c) {
      const int kcol = c * 16 + l15;
      const int base = kcol * 64;
      const int ksw = kcol & 7;
      const half8 k0 = *(const half8*)&KhS[base + (lhi ^ ksw) * 8];
      const half8 k1 = *(const half8*)&KhS[base + ((4 + lhi) ^ ksw) * 8];
#pragma unroll
      for (int qf = 0; qf < 2; ++qf) {
        f32x4v t = (f32x4v){0.f, 0.f, 0.f, 0.f};
        t = mfma16(qh[qf][0], k0, t);
        t = mfma16(ql[qf][0], k0, t);
        t = mfma16(qh[qf][1], k1, t);
        t = mfma16(ql[qf][1], k1, t);
        s[qf][c] = t;
      }
    }

    // ---- online softmax ----
    float mx[2][4];
#pragma unroll
    for (int qf = 0; qf < 2; ++qf)
#pragma unroll
      for (int r = 0; r < 4; ++r)
        mx[qf][r] = fmaxf(fmaxf(s[qf][0][r], s[qf][1][r]),
                          fmaxf(s[qf][2][r], s[qf][3][r]));
#pragma unroll
    for (int off = 1; off < 16; off <<= 1)
#pragma unroll
      for (int qf = 0; qf < 2; ++qf)
#pragma unroll
        for (int r = 0; r < 4; ++r)
          mx[qf][r] = fmaxf(mx[qf][r], __shfl_xor(mx[qf][r], off));

    // defer-max: skip rescale unless some row grew by > 8 (exp2 domain)
    int grow = 0;
#pragma unroll
    for (int qf = 0; qf < 2; ++qf)
#pragma unroll
      for (int r = 0; r < 4; ++r)
        grow |= (mx[qf][r] > m[qf][r] + 8.0f) ? 1 : 0;
    if (__any(grow)) {
#pragma unroll
      for (int qf = 0; qf < 2; ++qf)
#pragma unroll
        for (int r = 0; r < 4; ++r) {
          const float mn = fmaxf(m[qf][r], mx[qf][r]);
          const float sc = __builtin_amdgcn_exp2f(m[qf][r] - mn);
          m[qf][r] = mn;
          l[qf][r] *= sc;
#pragma unroll
          for (int c = 0; c < 4; ++c) O[qf][c][r] *= sc;
        }
    }

    float psum[2][4];
#pragma unroll
    for (int qf = 0; qf < 2; ++qf)
#pragma unroll
      for (int r = 0; r < 4; ++r) {
        psum[qf][r] = 0.f;
#pragma unroll
        for (int c = 0; c < 4; ++c) {
          const float p = __builtin_amdgcn_exp2f(s[qf][c][r] - m[qf][r]);
          psum[qf][r] += p;
          PS[w][qf * 16 + lhi * 4 + r][c * 16 + l15] = (_Float16)p;
        }
      }
#pragma unroll
    for (int off = 1; off < 16; off <<= 1)
#pragma unroll
      for (int qf = 0; qf < 2; ++qf)
#pragma unroll
        for (int r = 0; r < 4; ++r)
          psum[qf][r] += __shfl_xor(psum[qf][r], off);
#pragma unroll
    for (int qf = 0; qf < 2; ++qf)
#pragma unroll
      for (int r = 0; r < 4; ++r) l[qf][r] += psum[qf][r];

    // ---- O += P V (wave-private PS; compiler orders in-wave ds ops) ----
    half8 pa[2][2];
#pragma unroll
    for (int qf = 0; qf < 2; ++qf) {
      pa[qf][0] = *(const half8*)&PS[w][qf * 16 + l15][lhi * 8];
      pa[qf][1] = *(const half8*)&PS[w][qf * 16 + l15][32 + lhi * 8];
    }
#pragma unroll
    for (int c = 0; c < 4; ++c) {
      const int dcol = c * 16 + l15;
      const int base = dcol * 64;
      const int dsw = dcol & 7;
      const half8 v0 = *(const half8*)&VtS[base + (lhi ^ dsw) * 8];
      const half8 v1 = *(const half8*)&VtS[base + ((4 + lhi) ^ dsw) * 8];
#pragma unroll
      for (int qf = 0; qf < 2; ++qf) {
        O[qf][c] = mfma16(pa[qf][0], v0, O[qf][c]);
        O[qf][c] = mfma16(pa[qf][1], v1, O[qf][c]);
      }
    }
  }

  // ---- normalize + write merged heads as f16 hi/lo for proj GEMM ----
#pragma unroll
  for (int qf = 0; qf < 2; ++qf) {
    float inv[4];
#pragma unroll
    for (int r = 0; r < 4; ++r) inv[r] = 1.0f / l[qf][r];
#pragma unroll
    for (int c = 0; c < 4; ++c) {
#pragma unroll
      for (int r = 0; r < 4; ++r) {
        const int q = q0 + qf * 16 + lhi * 4 + r;
        const float v = O[qf][c][r] * inv[r];
        const _Float16 hi = (_Float16)v;
        const size_t idx =
            (size_t)(b * T_SEQ + q) * EMB + h * HD + c * 16 + l15;
        AOh[idx] = hi;
        AOl[idx] = (_Float16)(v - (float)hi);
      }
    }
  }
}

extern "C" void kernel_launch(void* const* d_in, const int* in_sizes, int n_in,
                              void* d_out, int out_size, void* d_ws,
                              size_t ws_size, hipStream_t stream) {
  const float* x = (const float*)d_in[0];
  const float* w_attn = (const float*)d_in[1];
  const float* b_attn = (const float*)d_in[2];
  const float* w_proj = (const float*)d_in[3];
  const float* b_proj = (const float*)d_in[4];
  float* out = (float*)d_out;

  const size_t SZX = (size_t)MROWS * EMB;  // 8388608
  const size_t SZWA = (size_t)THREE_EMB * EMB;
  const size_t SZWP = (size_t)EMB * EMB;

  _Float16* Xhi = (_Float16*)d_ws;
  _Float16* Xlo = Xhi + SZX;
  _Float16* WaHi = Xlo + SZX;
  _Float16* WaLo = WaHi + SZWA;
  _Float16* WpHi = WaLo + SZWA;
  _Float16* WpLo = WpHi + SZWP;
  _Float16* Qhi = WpLo + SZWP;
  _Float16* Qlo = Qhi + SZX;
  _Float16* Kh = Qlo + SZX;
  _Float16* Vt = Kh + SZX;  // total ~112 MiB
  // X region is dead after the QKV GEMM -> reuse for attention output
  _Float16* Ahi = Xhi;
  _Float16* Alo = Xlo;

  split_x<<<4096, 256, 0, stream>>>(x, Xhi, Xlo);
  tsplit_w<<<dim3(32, 96), 256, 0, stream>>>(w_attn, WaHi, WaLo, THREE_EMB);
  tsplit_w<<<dim3(32, 32), 256, 0, stream>>>(w_proj, WpHi, WpLo, EMB);

  mfma_gemm<0><<<dim3(64, 24), 256, 0, stream>>>(
      Xhi, Xlo, WaHi, WaLo, b_attn, nullptr, Qhi, Qlo, Kh, Vt);
  attn_kernel<<<dim3(16, NBH), 256, 0, stream>>>(Qhi, Qlo, Kh, Vt, Ahi, Alo);
  mfma_gemm<1><<<dim3(64, 8), 256, 0, stream>>>(
      Ahi, Alo, WpHi, WpLo, b_proj, out, nullptr, nullptr, nullptr, nullptr);
}

// Round 6
// 358.981 us; speedup vs baseline: 5.2718x; 1.1655x over previous
//
#include <hip/hip_runtime.h>
#include <hip/hip_bf16.h>

#define EMB 1024
#define THREE_EMB 3072
#define T_SEQ 2048
#define NB 4
#define NH 16
#define HD 64
#define MROWS 8192  // NB * T_SEQ
#define NBH 64      // NB * NH

// 0.125 * log2(e): fold score scale AND exp->exp2 conversion into Q
#define QSCALE 0.18033688011112042f

typedef _Float16 half8 __attribute__((ext_vector_type(8)));
typedef _Float16 half4v __attribute__((ext_vector_type(4)));
typedef float f32x4v __attribute__((ext_vector_type(4)));

static __device__ __forceinline__ f32x4v mfma16(half8 a, half8 b, f32x4v c) {
  return __builtin_amdgcn_mfma_f32_16x16x32_f16(a, b, c, 0, 0, 0);
}

// async global->LDS, 16B per lane. LDS dest = wave-uniform base + lane*16.
static __device__ __forceinline__ void gload16(const void* g, void* l) {
  __builtin_amdgcn_global_load_lds(
      (const __attribute__((address_space(1))) void*)g,
      (__attribute__((address_space(3))) void*)l, 16, 0, 0);
}

// ---------------------------------------------------------------------------
// Pre-pass: split x (fp32) into f16 hi/lo, 8 elems/thread.
// ---------------------------------------------------------------------------
__global__ __launch_bounds__(256) void split_x(const float* __restrict__ X,
                                               _Float16* __restrict__ H,
                                               _Float16* __restrict__ L) {
  const size_t i = ((size_t)blockIdx.x * 256 + threadIdx.x) * 8;
  const float4 a = *(const float4*)&X[i];
  const float4 b = *(const float4*)&X[i + 4];
  const float va[8] = {a.x, a.y, a.z, a.w, b.x, b.y, b.z, b.w};
  half8 h, l;
#pragma unroll
  for (int j = 0; j < 8; ++j) {
    const _Float16 hh = (_Float16)va[j];
    h[j] = hh;
    l[j] = (_Float16)(va[j] - (float)hh);
  }
  *(half8*)&H[i] = h;
  *(half8*)&L[i] = l;
}

// ---------------------------------------------------------------------------
// Pre-pass: W [1024][N] fp32 -> Wt hi/lo [N][1024] f16 (32x32 LDS transpose).
// ---------------------------------------------------------------------------
__global__ __launch_bounds__(256) void tsplit_w(const float* __restrict__ W,
                                                _Float16* __restrict__ Th,
                                                _Float16* __restrict__ Tl,
                                                int N) {
  __shared__ float tile[32][33];
  const int tid = threadIdx.x;
  const int k0 = blockIdx.x * 32;
  const int n0 = blockIdx.y * 32;
  const int c = tid & 31;
  const int r4 = (tid >> 5) * 4;
#pragma unroll
  for (int rr = 0; rr < 4; ++rr)
    tile[r4 + rr][c] = W[(size_t)(k0 + r4 + rr) * N + n0 + c];
  __syncthreads();
#pragma unroll
  for (int rr = 0; rr < 4; ++rr) {
    const float v = tile[c][r4 + rr];
    const _Float16 hi = (_Float16)v;
    Th[(size_t)(n0 + r4 + rr) * EMB + k0 + c] = hi;
    Tl[(size_t)(n0 + r4 + rr) * EMB + k0 + c] = (_Float16)(v - (float)hi);
  }
}

// ---------------------------------------------------------------------------
// MFMA split-f16 GEMM: C = A @ B^T + bias (3-term f16 split, fp32 accum).
// 128x128 tile, BK=64, 4 waves (2x2) of 64x64; global_load_lds staging with
// source-side inverse chunk-XOR swizzle, read-side swizzle -> <=2-way.
// MODE 0: QKV epilogue (Q hi/lo scaled, K single f16, V transposed f16).
// MODE 1: fp32 out + bias.
// ---------------------------------------------------------------------------
template <int MODE>
__global__ __launch_bounds__(256) void mfma_gemm(
    const _Float16* __restrict__ Ah, const _Float16* __restrict__ Al,
    const _Float16* __restrict__ Bh, const _Float16* __restrict__ Bl,
    const float* __restrict__ bias, float* __restrict__ OutF,
    _Float16* __restrict__ Qhi, _Float16* __restrict__ Qlo,
    _Float16* __restrict__ Kh, _Float16* __restrict__ Vt) {
  __shared__ __align__(16) _Float16 sAh[128 * 64];
  __shared__ __align__(16) _Float16 sAl[128 * 64];
  __shared__ __align__(16) _Float16 sBh[128 * 64];
  __shared__ __align__(16) _Float16 sBl[128 * 64];

  const int tid = threadIdx.x;
  const int w = tid >> 6;
  const int lane = tid & 63;
  const int l15 = lane & 15;
  const int lhi = lane >> 4;
  const int wm = w >> 1, wn = w & 1;
  const int m0 = blockIdx.x * 128;
  const int n0 = blockIdx.y * 128;

  const int rl = lane >> 3;
  const int cs8 = ((lane & 7) ^ rl) * 8;  // inverse-swizzled source k-offset
  const _Float16* gs;
  _Float16* ls;
  if (w == 0) {
    gs = Ah + (size_t)m0 * EMB; ls = sAh;
  } else if (w == 1) {
    gs = Al + (size_t)m0 * EMB; ls = sAl;
  } else if (w == 2) {
    gs = Bh + (size_t)n0 * EMB; ls = sBh;
  } else {
    gs = Bl + (size_t)n0 * EMB; ls = sBl;
  }
  const _Float16* gl = gs + (size_t)rl * EMB + cs8;

  f32x4v acc[4][4];
#pragma unroll
  for (int mi = 0; mi < 4; ++mi)
#pragma unroll
    for (int ni = 0; ni < 4; ++ni) acc[mi][ni] = (f32x4v){0.f, 0.f, 0.f, 0.f};

  const int sb0 = ((lhi) ^ (l15 & 7)) * 8;
  const int sb1 = ((4 + lhi) ^ (l15 & 7)) * 8;

  for (int k0 = 0; k0 < EMB; k0 += 64) {
    __syncthreads();
#pragma unroll
    for (int i = 0; i < 16; ++i)
      gload16(gl + k0 + i * 8 * EMB, ls + i * 512);
    __syncthreads();
#pragma unroll
    for (int kk = 0; kk < 2; ++kk) {
      const int sb = kk ? sb1 : sb0;
      half8 am[2][4], bn[2][4];
#pragma unroll
      for (int mi = 0; mi < 4; ++mi) {
        const int r = wm * 64 + mi * 16 + l15;
        am[0][mi] = *(const half8*)&sAh[r * 64 + sb];
        am[1][mi] = *(const half8*)&sAl[r * 64 + sb];
      }
#pragma unroll
      for (int ni = 0; ni < 4; ++ni) {
        const int r = wn * 64 + ni * 16 + l15;
        bn[0][ni] = *(const half8*)&sBh[r * 64 + sb];
        bn[1][ni] = *(const half8*)&sBl[r * 64 + sb];
      }
#pragma unroll
      for (int mi = 0; mi < 4; ++mi)
#pragma unroll
        for (int ni = 0; ni < 4; ++ni) {
          acc[mi][ni] = mfma16(am[0][mi], bn[0][ni], acc[mi][ni]);
          acc[mi][ni] = mfma16(am[1][mi], bn[0][ni], acc[mi][ni]);
          acc[mi][ni] = mfma16(am[0][mi], bn[1][ni], acc[mi][ni]);
        }
    }
  }

  // ---- epilogue ----  C layout: row=(lane>>4)*4+reg, col=lane&15
  const int gmB = m0 + wm * 64 + lhi * 4;
  const int gnB = n0 + wn * 64 + l15;
  if (MODE == 1) {
#pragma unroll
    for (int mi = 0; mi < 4; ++mi)
#pragma unroll
      for (int ni = 0; ni < 4; ++ni) {
        const int gn = gnB + ni * 16;
        const float bi = bias[gn];
#pragma unroll
        for (int r = 0; r < 4; ++r) {
          const int gm = gmB + mi * 16 + r;
          OutF[(size_t)gm * EMB + gn] = acc[mi][ni][r] + bi;
        }
      }
  } else {
    const int which = n0 >> 10;  // 0:Q 1:K 2:V, uniform per block
#pragma unroll
    for (int mi = 0; mi < 4; ++mi) {
#pragma unroll
      for (int ni = 0; ni < 4; ++ni) {
        const int gn = gnB + ni * 16;
        const float bi = bias[gn];
        const int d = gn & 63;
        const int h = (gn >> 6) & 15;
        const int gm0 = gmB + mi * 16;
        const int b = gm0 >> 11;
        const int t0 = gm0 & 2047;
        const int bh = b * NH + h;
        if (which == 2) {
          half4v hv;
#pragma unroll
          for (int r = 0; r < 4; ++r) hv[r] = (_Float16)(acc[mi][ni][r] + bi);
          *(half4v*)&Vt[((size_t)bh * HD + d) * T_SEQ + t0] = hv;  // [bh][d][t]
        } else if (which == 1) {
#pragma unroll
          for (int r = 0; r < 4; ++r) {
            const float v = acc[mi][ni][r] + bi;
            Kh[((size_t)bh * T_SEQ + t0 + r) * HD + d] = (_Float16)v;
          }
        } else {
#pragma unroll
          for (int r = 0; r < 4; ++r) {
            const float v = (acc[mi][ni][r] + bi) * QSCALE;
            const _Float16 hi = (_Float16)v;
            const size_t idx = ((size_t)bh * T_SEQ + t0 + r) * HD + d;
            Qhi[idx] = hi;
            Qlo[idx] = (_Float16)(v - (float)hi);
          }
        }
      }
    }
  }
}

// ---------------------------------------------------------------------------
// MFMA flash attention, swapped-operand form. Block = 4 waves x 32 q-rows.
// K-tile = 64 keys, double-buffered K/V in LDS, ONE barrier per tile
// (stage(next) issued after the barrier, overlapped with compute).
//   S^T = mfma(K, Qhi) + mfma(K, Qlo): C-layout => key=lhi*4+r, q=l15
//   => row softmax = in-lane reduce over 16 regs + shfl_xor(16,32).
//   P packed to f16 pairs (cvt_pkrtz), 4x ds_write_b64 per qf; psum from
//   ROUNDED P so the normalization is an exact convex combination.
//   O^T = mfma(V^T, P): d=c*16+lhi*4+r, q=l15; epilogue half4 stores.
// ---------------------------------------------------------------------------
__global__ __launch_bounds__(256) void attn_kernel(
    const _Float16* __restrict__ Qhi, const _Float16* __restrict__ Qlo,
    const _Float16* __restrict__ Kh, const _Float16* __restrict__ Vt,
    _Float16* __restrict__ AOh, _Float16* __restrict__ AOl) {
  __shared__ __align__(16) _Float16 KhS[2][64 * 64];
  __shared__ __align__(16) _Float16 VtS[2][64 * 64];
  __shared__ __align__(16) _Float16 PS[4][32][80];  // 160B rows (16B-aligned)

  const int tid = threadIdx.x;
  const int w = tid >> 6;
  const int lane = tid & 63;
  const int l15 = lane & 15;
  const int lhi = lane >> 4;
  const int sw = l15 & 7;
  const int bh = blockIdx.y;
  const int q0 = blockIdx.x * 128 + w * 32;
  const int b = bh >> 4;
  const int h = bh & 15;

  // Q B-fragments for 2 sub-tiles of 16 q (col=l15, k=d=lhi*8+j, m2*32)
  half8 qh[2][2], ql[2][2];
#pragma unroll
  for (int qf = 0; qf < 2; ++qf) {
    const size_t qb = ((size_t)bh * T_SEQ + q0 + qf * 16 + l15) * HD + lhi * 8;
#pragma unroll
    for (int m2 = 0; m2 < 2; ++m2) {
      qh[qf][m2] = *(const half8*)&Qhi[qb + m2 * 32];
      ql[qf][m2] = *(const half8*)&Qlo[qb + m2 * 32];
    }
  }

  f32x4v O[2][4];  // O^T: [qf][c], elem r -> d = c*16+lhi*4+r, q = l15
  float m[2], l[2];
#pragma unroll
  for (int qf = 0; qf < 2; ++qf) {
    m[qf] = -1e30f;
    l[qf] = 0.f;
#pragma unroll
    for (int c = 0; c < 4; ++c) O[qf][c] = (f32x4v){0.f, 0.f, 0.f, 0.f};
  }

  // staging: wave w stages K/V rows w*16 + i*8 + (lane>>3), slot lane&7;
  // source chunk = slot ^ (row&7)  (row&7 == lane>>3 here)
  const int so = lane >> 3;
  const int schunk = ((lane & 7) ^ so) * 8;
  const size_t kgb = (size_t)bh * T_SEQ * HD;
  const size_t vgb = (size_t)bh * HD * T_SEQ;
  const int rb = w * 16;

#define STAGE(buf, kt_)                                              \
  {                                                                  \
    _Pragma("unroll") for (int i = 0; i < 2; ++i) {                  \
      const int row = rb + i * 8 + so;                               \
      gload16(Kh + kgb + (size_t)((kt_) + row) * HD + schunk,        \
              &KhS[(buf)][(rb + i * 8) * 64]);                       \
      gload16(Vt + vgb + (size_t)row * T_SEQ + (kt_) + schunk,       \
              &VtS[(buf)][(rb + i * 8) * 64]);                       \
    }                                                                \
  }

  STAGE(0, 0);
  int cur = 0;

  for (int kt = 0; kt < T_SEQ; kt += 64) {
    __syncthreads();  // drains vmcnt (stage of buf[cur]) + joins all waves
    if (kt + 64 < T_SEQ) STAGE(cur ^ 1, kt + 64);

    // ---- S^T = K Q^T: s[qf][c][r] = S[key=c*16+lhi*4+r][q=qf*16+l15] ----
    f32x4v s[2][4];
#pragma unroll
    for (int c = 0; c < 4; ++c) {
      const int krow = c * 16 + l15;
      const half8 k0 = *(const half8*)&KhS[cur][krow * 64 + (lhi ^ sw) * 8];
      const half8 k1 =
          *(const half8*)&KhS[cur][krow * 64 + ((4 + lhi) ^ sw) * 8];
#pragma unroll
      for (int qf = 0; qf < 2; ++qf) {
        f32x4v t = (f32x4v){0.f, 0.f, 0.f, 0.f};
        t = mfma16(k0, qh[qf][0], t);
        t = mfma16(k0, ql[qf][0], t);
        t = mfma16(k1, qh[qf][1], t);
        t = mfma16(k1, ql[qf][1], t);
        s[qf][c] = t;
      }
    }

    // ---- online softmax: in-lane 16-value reduce + 2 shuffles ----
    float mx[2];
    int grow = 0;
#pragma unroll
    for (int qf = 0; qf < 2; ++qf) {
      float t0 = fmaxf(fmaxf(s[qf][0][0], s[qf][0][1]),
                       fmaxf(s[qf][0][2], s[qf][0][3]));
      float t1 = fmaxf(fmaxf(s[qf][1][0], s[qf][1][1]),
                       fmaxf(s[qf][1][2], s[qf][1][3]));
      float t2 = fmaxf(fmaxf(s[qf][2][0], s[qf][2][1]),
                       fmaxf(s[qf][2][2], s[qf][2][3]));
      float t3 = fmaxf(fmaxf(s[qf][3][0], s[qf][3][1]),
                       fmaxf(s[qf][3][2], s[qf][3][3]));
      float t = fmaxf(fmaxf(t0, t1), fmaxf(t2, t3));
      t = fmaxf(t, __shfl_xor(t, 16));
      t = fmaxf(t, __shfl_xor(t, 32));
      mx[qf] = t;
      grow |= (t > m[qf] + 8.0f) ? 1 : 0;
    }
    if (__any(grow)) {  // defer-max: rescale only on significant growth
#pragma unroll
      for (int qf = 0; qf < 2; ++qf) {
        const float mn = fmaxf(m[qf], mx[qf]);
        const float sc = __builtin_amdgcn_exp2f(m[qf] - mn);
        m[qf] = mn;
        l[qf] *= sc;
#pragma unroll
        for (int c = 0; c < 4; ++c) {
#pragma unroll
          for (int r = 0; r < 4; ++r) O[qf][c][r] *= sc;
        }
      }
    }

    // ---- P = exp2(S - m), pack f16 pairs, psum from ROUNDED values ----
#pragma unroll
    for (int qf = 0; qf < 2; ++qf) {
      float ps = 0.f;
      const int prow = qf * 16 + l15;
#pragma unroll
      for (int c = 0; c < 4; ++c) {
        const float p0 = __builtin_amdgcn_exp2f(s[qf][c][0] - m[qf]);
        const float p1 = __builtin_amdgcn_exp2f(s[qf][c][1] - m[qf]);
        const float p2 = __builtin_amdgcn_exp2f(s[qf][c][2] - m[qf]);
        const float p3 = __builtin_amdgcn_exp2f(s[qf][c][3] - m[qf]);
        const auto e0 = __builtin_amdgcn_cvt_pkrtz(p0, p1);  // __fp16 x2
        const auto e1 = __builtin_amdgcn_cvt_pkrtz(p2, p3);
        half4v pw;
        pw[0] = (_Float16)e0[0];
        pw[1] = (_Float16)e0[1];
        pw[2] = (_Float16)e1[0];
        pw[3] = (_Float16)e1[1];
        ps += (float)pw[0] + (float)pw[1] + (float)pw[2] + (float)pw[3];
        const int ch = (2 * c + (lhi >> 1)) ^ sw;
        *(half4v*)&PS[w][prow][ch * 8 + (lhi & 1) * 4] = pw;
      }
      ps += __shfl_xor(ps, 16);
      ps += __shfl_xor(ps, 32);
      l[qf] += ps;
    }

    // ---- O^T += V^T P (wave-private PS; in-wave ds ordering) ----
    half8 pb[2][2];
#pragma unroll
    for (int qf = 0; qf < 2; ++qf)
#pragma unroll
      for (int m2 = 0; m2 < 2; ++m2) {
        const int ch = (lhi + 4 * m2) ^ sw;
        pb[qf][m2] = *(const half8*)&PS[w][qf * 16 + l15][ch * 8];
      }
#pragma unroll
    for (int c = 0; c < 4; ++c) {
      const int vrow = c * 16 + l15;
      const half8 v0 = *(const half8*)&VtS[cur][vrow * 64 + (lhi ^ sw) * 8];
      const half8 v1 =
          *(const half8*)&VtS[cur][vrow * 64 + ((4 + lhi) ^ sw) * 8];
#pragma unroll
      for (int qf = 0; qf < 2; ++qf) {
        O[qf][c] = mfma16(v0, pb[qf][0], O[qf][c]);
        O[qf][c] = mfma16(v1, pb[qf][1], O[qf][c]);
      }
    }
    cur ^= 1;
  }

  // ---- normalize + write merged heads as f16 hi/lo (half4 stores) ----
#pragma unroll
  for (int qf = 0; qf < 2; ++qf) {
    const float inv = 1.0f / l[qf];
    const size_t rowb =
        (size_t)(b * T_SEQ + q0 + qf * 16 + l15) * EMB + h * HD + lhi * 4;
#pragma unroll
    for (int c = 0; c < 4; ++c) {
      half4v hv, lv;
#pragma unroll
      for (int r = 0; r < 4; ++r) {
        const float v = O[qf][c][r] * inv;
        hv[r] = (_Float16)v;
        lv[r] = (_Float16)(v - (float)hv[r]);
      }
      *(half4v*)&AOh[rowb + c * 16] = hv;
      *(half4v*)&AOl[rowb + c * 16] = lv;
    }
  }
#undef STAGE
}

extern "C" void kernel_launch(void* const* d_in, const int* in_sizes, int n_in,
                              void* d_out, int out_size, void* d_ws,
                              size_t ws_size, hipStream_t stream) {
  const float* x = (const float*)d_in[0];
  const float* w_attn = (const float*)d_in[1];
  const float* b_attn = (const float*)d_in[2];
  const float* w_proj = (const float*)d_in[3];
  const float* b_proj = (const float*)d_in[4];
  float* out = (float*)d_out;

  const size_t SZX = (size_t)MROWS * EMB;  // 8388608
  const size_t SZWA = (size_t)THREE_EMB * EMB;
  const size_t SZWP = (size_t)EMB * EMB;

  _Float16* Xhi = (_Float16*)d_ws;
  _Float16* Xlo = Xhi + SZX;
  _Float16* WaHi = Xlo + SZX;
  _Float16* WaLo = WaHi + SZWA;
  _Float16* WpHi = WaLo + SZWA;
  _Float16* WpLo = WpHi + SZWP;
  _Float16* Qhi = WpLo + SZWP;
  _Float16* Qlo = Qhi + SZX;
  _Float16* Kh = Qlo + SZX;
  _Float16* Vt = Kh + SZX;  // total ~112 MiB
  // X region is dead after the QKV GEMM -> reuse for attention output
  _Float16* Ahi = Xhi;
  _Float16* Alo = Xlo;

  split_x<<<4096, 256, 0, stream>>>(x, Xhi, Xlo);
  tsplit_w<<<dim3(32, 96), 256, 0, stream>>>(w_attn, WaHi, WaLo, THREE_EMB);
  tsplit_w<<<dim3(32, 32), 256, 0, stream>>>(w_proj, WpHi, WpLo, EMB);

  mfma_gemm<0><<<dim3(64, 24), 256, 0, stream>>>(
      Xhi, Xlo, WaHi, WaLo, b_attn, nullptr, Qhi, Qlo, Kh, Vt);
  attn_kernel<<<dim3(16, NBH), 256, 0, stream>>>(Qhi, Qlo, Kh, Vt, Ahi, Alo);
  mfma_gemm<1><<<dim3(64, 8), 256, 0, stream>>>(
      Ahi, Alo, WpHi, WpLo, b_proj, out, nullptr, nullptr, nullptr, nullptr);
}

// Round 7
// 342.634 us; speedup vs baseline: 5.5233x; 1.0477x over previous
//
#include <hip/hip_runtime.h>
#include <hip/hip_bf16.h>

#define EMB 1024
#define THREE_EMB 3072
#define T_SEQ 2048
#define NB 4
#define NH 16
#define HD 64
#define MROWS 8192  // NB * T_SEQ
#define NBH 64      // NB * NH

// 0.125 * log2(e): fold score scale AND exp->exp2 conversion into Q
#define QSCALE 0.18033688011112042f

typedef _Float16 half8 __attribute__((ext_vector_type(8)));
typedef _Float16 half4v __attribute__((ext_vector_type(4)));
typedef float f32x4v __attribute__((ext_vector_type(4)));

static __device__ __forceinline__ f32x4v mfma16(half8 a, half8 b, f32x4v c) {
  return __builtin_amdgcn_mfma_f32_16x16x32_f16(a, b, c, 0, 0, 0);
}

// async global->LDS, 16B per lane. LDS dest = wave-uniform base + lane*16.
static __device__ __forceinline__ void gload16(const void* g, void* l) {
  __builtin_amdgcn_global_load_lds(
      (const __attribute__((address_space(1))) void*)g,
      (__attribute__((address_space(3))) void*)l, 16, 0, 0);
}

// ---------------------------------------------------------------------------
// Pre-pass: split x (fp32) into f16 hi/lo, 8 elems/thread.
// ---------------------------------------------------------------------------
__global__ __launch_bounds__(256) void split_x(const float* __restrict__ X,
                                               _Float16* __restrict__ H,
                                               _Float16* __restrict__ L) {
  const size_t i = ((size_t)blockIdx.x * 256 + threadIdx.x) * 8;
  const float4 a = *(const float4*)&X[i];
  const float4 b = *(const float4*)&X[i + 4];
  const float va[8] = {a.x, a.y, a.z, a.w, b.x, b.y, b.z, b.w};
  half8 h, l;
#pragma unroll
  for (int j = 0; j < 8; ++j) {
    const _Float16 hh = (_Float16)va[j];
    h[j] = hh;
    l[j] = (_Float16)(va[j] - (float)hh);
  }
  *(half8*)&H[i] = h;
  *(half8*)&L[i] = l;
}

// ---------------------------------------------------------------------------
// Pre-pass: W [1024][N] fp32 -> Wt hi/lo [N][1024] f16 (32x32 LDS transpose).
// ---------------------------------------------------------------------------
__global__ __launch_bounds__(256) void tsplit_w(const float* __restrict__ W,
                                                _Float16* __restrict__ Th,
                                                _Float16* __restrict__ Tl,
                                                int N) {
  __shared__ float tile[32][33];
  const int tid = threadIdx.x;
  const int k0 = blockIdx.x * 32;
  const int n0 = blockIdx.y * 32;
  const int c = tid & 31;
  const int r4 = (tid >> 5) * 4;
#pragma unroll
  for (int rr = 0; rr < 4; ++rr)
    tile[r4 + rr][c] = W[(size_t)(k0 + r4 + rr) * N + n0 + c];
  __syncthreads();
#pragma unroll
  for (int rr = 0; rr < 4; ++rr) {
    const float v = tile[c][r4 + rr];
    const _Float16 hi = (_Float16)v;
    Th[(size_t)(n0 + r4 + rr) * EMB + k0 + c] = hi;
    Tl[(size_t)(n0 + r4 + rr) * EMB + k0 + c] = (_Float16)(v - (float)hi);
  }
}

// ---------------------------------------------------------------------------
// MFMA split-f16 GEMM: C = A @ B^T + bias (3-term f16 split, fp32 accum).
// 128x128 tile, BK=64, 4 waves (2x2) of 64x64; global_load_lds staging with
// source-side inverse chunk-XOR swizzle, read-side swizzle -> <=2-way.
// MODE 0: QKV epilogue (Q hi/lo scaled, K single f16, V transposed f16).
// MODE 1: fp32 out + bias.
// ---------------------------------------------------------------------------
template <int MODE>
__global__ __launch_bounds__(256) void mfma_gemm(
    const _Float16* __restrict__ Ah, const _Float16* __restrict__ Al,
    const _Float16* __restrict__ Bh, const _Float16* __restrict__ Bl,
    const float* __restrict__ bias, float* __restrict__ OutF,
    _Float16* __restrict__ Qhi, _Float16* __restrict__ Qlo,
    _Float16* __restrict__ Kh, _Float16* __restrict__ Vt) {
  __shared__ __align__(16) _Float16 sAh[128 * 64];
  __shared__ __align__(16) _Float16 sAl[128 * 64];
  __shared__ __align__(16) _Float16 sBh[128 * 64];
  __shared__ __align__(16) _Float16 sBl[128 * 64];

  const int tid = threadIdx.x;
  const int w = tid >> 6;
  const int lane = tid & 63;
  const int l15 = lane & 15;
  const int lhi = lane >> 4;
  const int wm = w >> 1, wn = w & 1;
  const int m0 = blockIdx.x * 128;
  const int n0 = blockIdx.y * 128;

  const int rl = lane >> 3;
  const int cs8 = ((lane & 7) ^ rl) * 8;  // inverse-swizzled source k-offset
  const _Float16* gs;
  _Float16* ls;
  if (w == 0) {
    gs = Ah + (size_t)m0 * EMB; ls = sAh;
  } else if (w == 1) {
    gs = Al + (size_t)m0 * EMB; ls = sAl;
  } else if (w == 2) {
    gs = Bh + (size_t)n0 * EMB; ls = sBh;
  } else {
    gs = Bl + (size_t)n0 * EMB; ls = sBl;
  }
  const _Float16* gl = gs + (size_t)rl * EMB + cs8;

  f32x4v acc[4][4];
#pragma unroll
  for (int mi = 0; mi < 4; ++mi)
#pragma unroll
    for (int ni = 0; ni < 4; ++ni) acc[mi][ni] = (f32x4v){0.f, 0.f, 0.f, 0.f};

  const int sb0 = ((lhi) ^ (l15 & 7)) * 8;
  const int sb1 = ((4 + lhi) ^ (l15 & 7)) * 8;

  for (int k0 = 0; k0 < EMB; k0 += 64) {
    __syncthreads();
#pragma unroll
    for (int i = 0; i < 16; ++i)
      gload16(gl + k0 + i * 8 * EMB, ls + i * 512);
    __syncthreads();
#pragma unroll
    for (int kk = 0; kk < 2; ++kk) {
      const int sb = kk ? sb1 : sb0;
      half8 am[2][4], bn[2][4];
#pragma unroll
      for (int mi = 0; mi < 4; ++mi) {
        const int r = wm * 64 + mi * 16 + l15;
        am[0][mi] = *(const half8*)&sAh[r * 64 + sb];
        am[1][mi] = *(const half8*)&sAl[r * 64 + sb];
      }
#pragma unroll
      for (int ni = 0; ni < 4; ++ni) {
        const int r = wn * 64 + ni * 16 + l15;
        bn[0][ni] = *(const half8*)&sBh[r * 64 + sb];
        bn[1][ni] = *(const half8*)&sBl[r * 64 + sb];
      }
#pragma unroll
      for (int mi = 0; mi < 4; ++mi)
#pragma unroll
        for (int ni = 0; ni < 4; ++ni) {
          acc[mi][ni] = mfma16(am[0][mi], bn[0][ni], acc[mi][ni]);
          acc[mi][ni] = mfma16(am[1][mi], bn[0][ni], acc[mi][ni]);
          acc[mi][ni] = mfma16(am[0][mi], bn[1][ni], acc[mi][ni]);
        }
    }
  }

  // ---- epilogue ----  C layout: row=(lane>>4)*4+reg, col=lane&15
  const int gmB = m0 + wm * 64 + lhi * 4;
  const int gnB = n0 + wn * 64 + l15;
  if (MODE == 1) {
#pragma unroll
    for (int mi = 0; mi < 4; ++mi)
#pragma unroll
      for (int ni = 0; ni < 4; ++ni) {
        const int gn = gnB + ni * 16;
        const float bi = bias[gn];
#pragma unroll
        for (int r = 0; r < 4; ++r) {
          const int gm = gmB + mi * 16 + r;
          OutF[(size_t)gm * EMB + gn] = acc[mi][ni][r] + bi;
        }
      }
  } else {
    const int which = n0 >> 10;  // 0:Q 1:K 2:V, uniform per block
#pragma unroll
    for (int mi = 0; mi < 4; ++mi) {
#pragma unroll
      for (int ni = 0; ni < 4; ++ni) {
        const int gn = gnB + ni * 16;
        const float bi = bias[gn];
        const int d = gn & 63;
        const int h = (gn >> 6) & 15;
        const int gm0 = gmB + mi * 16;
        const int b = gm0 >> 11;
        const int t0 = gm0 & 2047;
        const int bh = b * NH + h;
        if (which == 2) {
          half4v hv;
#pragma unroll
          for (int r = 0; r < 4; ++r) hv[r] = (_Float16)(acc[mi][ni][r] + bi);
          *(half4v*)&Vt[((size_t)bh * HD + d) * T_SEQ + t0] = hv;  // [bh][d][t]
        } else if (which == 1) {
#pragma unroll
          for (int r = 0; r < 4; ++r) {
            const float v = acc[mi][ni][r] + bi;
            Kh[((size_t)bh * T_SEQ + t0 + r) * HD + d] = (_Float16)v;
          }
        } else {
#pragma unroll
          for (int r = 0; r < 4; ++r) {
            const float v = (acc[mi][ni][r] + bi) * QSCALE;
            const _Float16 hi = (_Float16)v;
            const size_t idx = ((size_t)bh * T_SEQ + t0 + r) * HD + d;
            Qhi[idx] = hi;
            Qlo[idx] = (_Float16)(v - (float)hi);
          }
        }
      }
    }
  }
}

// ---------------------------------------------------------------------------
// MFMA flash attention, swapped-operand form. Block = 4 waves x 32 q-rows.
// K-tile = 64 keys. THREE-buffer K/V rotation with counted vmcnt(4) + raw
// s_barrier: stage(t+2) issued after barrier(t); buffer written at t+2 is the
// one read at t-1 (reads complete before barrier(t) by construction); each
// wave's vmcnt(4) before barrier guarantees its tile-t stage landed.
//   S^T = mfma(K, Qhi/Qlo); softmax rows in-lane (16 regs) + 2 shuffles.
//   P -> f16 (cvt_pkrtz) -> PS (slot swizzle incl. l15-bit3 -> no 2-way).
//   psum via mfma(ones, P) -- exact sum of the rounded P the PV uses.
//   O^T = mfma(V^T, P); qf-serialized PV so PS is [4][16][80] (LDS fits).
// XCD-aware 1D grid: all 16 q-blocks of a bh on one XCD (K/V L2-resident).
// ---------------------------------------------------------------------------
__global__ __launch_bounds__(256) void attn_kernel(
    const _Float16* __restrict__ Qhi, const _Float16* __restrict__ Qlo,
    const _Float16* __restrict__ Kh, const _Float16* __restrict__ Vt,
    _Float16* __restrict__ AOh, _Float16* __restrict__ AOl) {
  __shared__ __align__(16) _Float16 KhS[3][64 * 64];
  __shared__ __align__(16) _Float16 VtS[3][64 * 64];
  __shared__ __align__(16) _Float16 PS[4][16][80];

  const int tid = threadIdx.x;
  const int w = tid >> 6;
  const int lane = tid & 63;
  const int l15 = lane & 15;
  const int lhi = lane >> 4;
  const int sw = l15 & 7;
  const int swz = sw ^ ((l15 >> 3) << 2);  // PS slot swizzle (bank-complete)

  // XCD swizzle: xcd = bid&7 gets bh in [8*xcd, 8*xcd+8), all 16 q-blocks
  const int bid = blockIdx.x;
  const int idx = bid >> 3;
  const int bh = (bid & 7) * 8 + (idx & 7);
  const int qb = idx >> 3;
  const int q0 = qb * 128 + w * 32;
  const int b = bh >> 4;
  const int h = bh & 15;

  // Q B-fragments for 2 sub-tiles of 16 q (col=l15, k=d=lhi*8+j, m2*32)
  half8 qh[2][2], ql[2][2];
#pragma unroll
  for (int qf = 0; qf < 2; ++qf) {
    const size_t qbase =
        ((size_t)bh * T_SEQ + q0 + qf * 16 + l15) * HD + lhi * 8;
#pragma unroll
    for (int m2 = 0; m2 < 2; ++m2) {
      qh[qf][m2] = *(const half8*)&Qhi[qbase + m2 * 32];
      ql[qf][m2] = *(const half8*)&Qlo[qbase + m2 * 32];
    }
  }

  half8 ones;
#pragma unroll
  for (int j = 0; j < 8; ++j) ones[j] = (_Float16)1.0f;

  f32x4v O[2][4];  // O^T: [qf][c], elem r -> d = c*16+lhi*4+r, q = l15
  float m[2], l[2];
#pragma unroll
  for (int qf = 0; qf < 2; ++qf) {
    m[qf] = -1e30f;
    l[qf] = 0.f;
#pragma unroll
    for (int c = 0; c < 4; ++c) O[qf][c] = (f32x4v){0.f, 0.f, 0.f, 0.f};
  }

  // staging: wave w stages K/V rows w*16 + i*8 + (lane>>3), slot lane&7;
  // source chunk = slot ^ (row&7)  (row&7 == lane>>3 here)
  const int so = lane >> 3;
  const int schunk = ((lane & 7) ^ so) * 8;
  const size_t kgb = (size_t)bh * T_SEQ * HD;
  const size_t vgb = (size_t)bh * HD * T_SEQ;
  const int rb = w * 16;

#define STAGE(buf, kt_)                                              \
  {                                                                  \
    _Pragma("unroll") for (int i = 0; i < 2; ++i) {                  \
      const int row = rb + i * 8 + so;                               \
      gload16(Kh + kgb + (size_t)((kt_) + row) * HD + schunk,        \
              &KhS[(buf)][(rb + i * 8) * 64]);                       \
      gload16(Vt + vgb + (size_t)row * T_SEQ + (kt_) + schunk,       \
              &VtS[(buf)][(rb + i * 8) * 64]);                       \
    }                                                                \
  }

  STAGE(0, 0);
  STAGE(1, 64);
  int cur = 0;

  for (int kt = 0; kt < T_SEQ; kt += 64) {
    if (kt + 64 < T_SEQ) {
      asm volatile("s_waitcnt vmcnt(4)" ::: "memory");
    } else {
      asm volatile("s_waitcnt vmcnt(0)" ::: "memory");
    }
    __builtin_amdgcn_s_barrier();
    __builtin_amdgcn_sched_barrier(0);
    if (kt + 128 < T_SEQ) {
      const int stb = (cur == 0) ? 2 : cur - 1;  // (cur+2)%3
      STAGE(stb, kt + 128);
    }

    // ---- S^T = K Q^T: s[qf][c][r] = S[key=c*16+lhi*4+r][q=qf*16+l15] ----
    f32x4v s[2][4];
    __builtin_amdgcn_s_setprio(1);
#pragma unroll
    for (int c = 0; c < 4; ++c) {
      const int krow = c * 16 + l15;
      const half8 k0 = *(const half8*)&KhS[cur][krow * 64 + (lhi ^ sw) * 8];
      const half8 k1 =
          *(const half8*)&KhS[cur][krow * 64 + ((4 + lhi) ^ sw) * 8];
#pragma unroll
      for (int qf = 0; qf < 2; ++qf) {
        f32x4v t = (f32x4v){0.f, 0.f, 0.f, 0.f};
        t = mfma16(k0, qh[qf][0], t);
        t = mfma16(k0, ql[qf][0], t);
        t = mfma16(k1, qh[qf][1], t);
        t = mfma16(k1, ql[qf][1], t);
        s[qf][c] = t;
      }
    }
    __builtin_amdgcn_s_setprio(0);

    // V tile -> regs once (shared by both qf)
    half8 vv[4][2];
#pragma unroll
    for (int c = 0; c < 4; ++c) {
      const int vrow = c * 16 + l15;
      vv[c][0] = *(const half8*)&VtS[cur][vrow * 64 + (lhi ^ sw) * 8];
      vv[c][1] = *(const half8*)&VtS[cur][vrow * 64 + ((4 + lhi) ^ sw) * 8];
    }

    // ---- online softmax max: in-lane 16-value reduce + 2 shuffles ----
    float mx[2];
    int grow = 0;
#pragma unroll
    for (int qf = 0; qf < 2; ++qf) {
      float t0 = fmaxf(fmaxf(s[qf][0][0], s[qf][0][1]),
                       fmaxf(s[qf][0][2], s[qf][0][3]));
      float t1 = fmaxf(fmaxf(s[qf][1][0], s[qf][1][1]),
                       fmaxf(s[qf][1][2], s[qf][1][3]));
      float t2 = fmaxf(fmaxf(s[qf][2][0], s[qf][2][1]),
                       fmaxf(s[qf][2][2], s[qf][2][3]));
      float t3 = fmaxf(fmaxf(s[qf][3][0], s[qf][3][1]),
                       fmaxf(s[qf][3][2], s[qf][3][3]));
      float t = fmaxf(fmaxf(t0, t1), fmaxf(t2, t3));
      t = fmaxf(t, __shfl_xor(t, 16));
      t = fmaxf(t, __shfl_xor(t, 32));
      mx[qf] = t;
      grow |= (t > m[qf] + 8.0f) ? 1 : 0;
    }
    if (__any(grow)) {  // defer-max: rescale only on significant growth
#pragma unroll
      for (int qf = 0; qf < 2; ++qf) {
        const float mn = fmaxf(m[qf], mx[qf]);
        const float sc = __builtin_amdgcn_exp2f(m[qf] - mn);
        m[qf] = mn;
        l[qf] *= sc;
#pragma unroll
        for (int c = 0; c < 4; ++c) {
#pragma unroll
          for (int r = 0; r < 4; ++r) O[qf][c][r] *= sc;
        }
      }
    }

    // ---- per qf: P->f16->PS, psum via ones-MFMA, O^T += V^T P ----
#pragma unroll
    for (int qf = 0; qf < 2; ++qf) {
#pragma unroll
      for (int c = 0; c < 4; ++c) {
        const float p0 = __builtin_amdgcn_exp2f(s[qf][c][0] - m[qf]);
        const float p1 = __builtin_amdgcn_exp2f(s[qf][c][1] - m[qf]);
        const float p2 = __builtin_amdgcn_exp2f(s[qf][c][2] - m[qf]);
        const float p3 = __builtin_amdgcn_exp2f(s[qf][c][3] - m[qf]);
        const auto e0 = __builtin_amdgcn_cvt_pkrtz(p0, p1);  // __fp16 x2
        const auto e1 = __builtin_amdgcn_cvt_pkrtz(p2, p3);
        half4v pw;
        pw[0] = (_Float16)e0[0];
        pw[1] = (_Float16)e0[1];
        pw[2] = (_Float16)e1[0];
        pw[3] = (_Float16)e1[1];
        const int slot = (2 * c + (lhi >> 1)) ^ swz;
        *(half4v*)&PS[w][l15][slot * 8 + (lhi & 1) * 4] = pw;
      }
      const half8 pb0 = *(const half8*)&PS[w][l15][((lhi) ^ swz) * 8];
      const half8 pb1 = *(const half8*)&PS[w][l15][((lhi + 4) ^ swz) * 8];
      f32x4v ls = (f32x4v){0.f, 0.f, 0.f, 0.f};
      ls = mfma16(ones, pb0, ls);
      ls = mfma16(ones, pb1, ls);
      __builtin_amdgcn_s_setprio(1);
#pragma unroll
      for (int c = 0; c < 4; ++c) {
        O[qf][c] = mfma16(vv[c][0], pb0, O[qf][c]);
        O[qf][c] = mfma16(vv[c][1], pb1, O[qf][c]);
      }
      __builtin_amdgcn_s_setprio(0);
      l[qf] += ls[0];
    }
    cur = (cur == 2) ? 0 : cur + 1;
  }

  // ---- normalize + write merged heads as f16 hi/lo (half4 stores) ----
#pragma unroll
  for (int qf = 0; qf < 2; ++qf) {
    const float inv = 1.0f / l[qf];
    const size_t rowb =
        (size_t)(b * T_SEQ + q0 + qf * 16 + l15) * EMB + h * HD + lhi * 4;
#pragma unroll
    for (int c = 0; c < 4; ++c) {
      half4v hv, lv;
#pragma unroll
      for (int r = 0; r < 4; ++r) {
        const float v = O[qf][c][r] * inv;
        hv[r] = (_Float16)v;
        lv[r] = (_Float16)(v - (float)hv[r]);
      }
      *(half4v*)&AOh[rowb + c * 16] = hv;
      *(half4v*)&AOl[rowb + c * 16] = lv;
    }
  }
#undef STAGE
}

extern "C" void kernel_launch(void* const* d_in, const int* in_sizes, int n_in,
                              void* d_out, int out_size, void* d_ws,
                              size_t ws_size, hipStream_t stream) {
  const float* x = (const float*)d_in[0];
  const float* w_attn = (const float*)d_in[1];
  const float* b_attn = (const float*)d_in[2];
  const float* w_proj = (const float*)d_in[3];
  const float* b_proj = (const float*)d_in[4];
  float* out = (float*)d_out;

  const size_t SZX = (size_t)MROWS * EMB;  // 8388608
  const size_t SZWA = (size_t)THREE_EMB * EMB;
  const size_t SZWP = (size_t)EMB * EMB;

  _Float16* Xhi = (_Float16*)d_ws;
  _Float16* Xlo = Xhi + SZX;
  _Float16* WaHi = Xlo + SZX;
  _Float16* WaLo = WaHi + SZWA;
  _Float16* WpHi = WaLo + SZWA;
  _Float16* WpLo = WpHi + SZWP;
  _Float16* Qhi = WpLo + SZWP;
  _Float16* Qlo = Qhi + SZX;
  _Float16* Kh = Qlo + SZX;
  _Float16* Vt = Kh + SZX;  // total ~112 MiB
  // X region is dead after the QKV GEMM -> reuse for attention output
  _Float16* Ahi = Xhi;
  _Float16* Alo = Xlo;

  split_x<<<4096, 256, 0, stream>>>(x, Xhi, Xlo);
  tsplit_w<<<dim3(32, 96), 256, 0, stream>>>(w_attn, WaHi, WaLo, THREE_EMB);
  tsplit_w<<<dim3(32, 32), 256, 0, stream>>>(w_proj, WpHi, WpLo, EMB);

  mfma_gemm<0><<<dim3(64, 24), 256, 0, stream>>>(
      Xhi, Xlo, WaHi, WaLo, b_attn, nullptr, Qhi, Qlo, Kh, Vt);
  attn_kernel<<<dim3(1024), 256, 0, stream>>>(Qhi, Qlo, Kh, Vt, Ahi, Alo);
  mfma_gemm<1><<<dim3(64, 8), 256, 0, stream>>>(
      Ahi, Alo, WpHi, WpLo, b_proj, out, nullptr, nullptr, nullptr, nullptr);
}